// Round 2
// baseline (953.688 us; speedup 1.0000x reference)
//
#include <hip/hip_runtime.h>

#define N_NODES 100000
#define NEDGE   1600000
#define NHID    128
#define NCLASS  40

using bf16x8 = __attribute__((ext_vector_type(8))) short;
using f32x4  = __attribute__((ext_vector_type(4))) float;

__device__ __forceinline__ float bf2f(unsigned short s) {
    unsigned u = ((unsigned)s) << 16; float f; __builtin_memcpy(&f, &u, 4); return f;
}
__device__ __forceinline__ unsigned short f2bf(float f) {
    unsigned u; __builtin_memcpy(&u, &f, 4);
    u = u + 0x7fffu + ((u >> 16) & 1u);          // RNE
    return (unsigned short)(u >> 16);
}

// ---------------- CSR build ----------------
__global__ void k_zero(int* __restrict__ p, int n) {
    int i = blockIdx.x * 256 + threadIdx.x;
    if (i < n) p[i] = 0;
}

__global__ void k_count(const int* __restrict__ ei, int* __restrict__ cnt) {
    int e = blockIdx.x * 256 + threadIdx.x;
    if (e < NEDGE) atomicAdd(&cnt[ei[NEDGE + e]], 1);   // dst row of edge_index
}

// block scans 1024 elements (256 thr x 4)
__global__ void k_scan1(const int* __restrict__ cnt, int* __restrict__ rp, int* __restrict__ bsum) {
    __shared__ int sh[256];
    int t = threadIdx.x, base = blockIdx.x * 1024;
    int v[4]; int s = 0;
    for (int k = 0; k < 4; ++k) { int i = base + t * 4 + k; v[k] = (i < N_NODES) ? cnt[i] : 0; s += v[k]; }
    sh[t] = s; __syncthreads();
    for (int off = 1; off < 256; off <<= 1) {
        int x = (t >= off) ? sh[t - off] : 0;
        __syncthreads();
        sh[t] += x;
        __syncthreads();
    }
    int excl = sh[t] - s;
    for (int k = 0; k < 4; ++k) { int i = base + t * 4 + k; if (i < N_NODES) rp[i] = excl; excl += v[k]; }
    if (t == 255) bsum[blockIdx.x] = sh[255];
}

__global__ void k_scan2(int* __restrict__ bsum, int nb) {
    __shared__ int sh[256];
    int t = threadIdx.x;
    int v = (t < nb) ? bsum[t] : 0;
    sh[t] = v; __syncthreads();
    for (int off = 1; off < 256; off <<= 1) {
        int x = (t >= off) ? sh[t - off] : 0;
        __syncthreads();
        sh[t] += x;
        __syncthreads();
    }
    if (t < nb) bsum[t] = sh[t] - v;   // exclusive block offsets
}

__global__ void k_scan3(int* __restrict__ rp, const int* __restrict__ bsum) {
    int base = blockIdx.x * 1024;
    int off = bsum[blockIdx.x];
    for (int k = 0; k < 4; ++k) {
        int i = base + threadIdx.x * 4 + k;
        if (i < N_NODES) rp[i] += off;
    }
    if (blockIdx.x == 0 && threadIdx.x == 0) rp[N_NODES] = NEDGE;
}

__global__ void k_fill(const int* __restrict__ ei, const int* __restrict__ rp,
                       int* __restrict__ cur, int* __restrict__ colv) {
    int e = blockIdx.x * 256 + threadIdx.x;
    if (e < NEDGE) {
        int d = ei[NEDGE + e];
        int p = atomicAdd(&cur[d], 1);
        colv[rp[d] + p] = ei[e];
    }
}

// ---------------- weight prep: transpose + cvt to bf16, wt[o][k] = w[k][o] ----------------
__global__ void k_wprep(const float* __restrict__ w, unsigned short* __restrict__ wt,
                        int K, int O, int Opad) {
    int idx = blockIdx.x * 256 + threadIdx.x;
    if (idx >= K * Opad) return;
    int o = idx / K, k = idx - o * K;
    float v = (o < O) ? w[k * O + o] : 0.f;
    wt[idx] = f2bf(v);
}

// ---------------- x -> sliced bf16 layout [8][N][16] ----------------
__global__ void k_xprep(const float* __restrict__ x, unsigned short* __restrict__ xs) {
    int s = blockIdx.x & 7;
    int rest = (blockIdx.x >> 3) * 256 + threadIdx.x;   // word index within slice, N*8 words
    if (rest >= N_NODES * 8) return;
    int n = rest >> 3, wrd = rest & 7;
    float2 v = *(const float2*)(x + (size_t)n * 128 + s * 16 + wrd * 2);
    ((unsigned*)xs)[(size_t)s * N_NODES * 8 + rest] =
        (unsigned)f2bf(v.x) | ((unsigned)f2bf(v.y) << 16);
}

// ---------------- aggregation, sliced: t[s][i] = F[s][i] + sum_j F[s][j] ----------------
// slice = blockIdx & 7 -> XCD-pinned; per-XCD working set 3.2MB < 4MB L2.
// 8 edges in flight per wave (sub = lane>>3), 8 lanes x 4B cover the 32B slice.
__global__ __launch_bounds__(256) void k_aggs(const unsigned short* __restrict__ feat,
                                              unsigned short* __restrict__ tout,
                                              const int* __restrict__ rp,
                                              const int* __restrict__ colv) {
    const int s = blockIdx.x & 7;
    const int chunk = blockIdx.x >> 3;
    const int w = threadIdx.x >> 6, lane = threadIdx.x & 63;
    const int sub = lane >> 3, c = lane & 7;
    const unsigned* fs = (const unsigned*)feat + (size_t)s * N_NODES * 8;
    unsigned* ts = (unsigned*)tout + (size_t)s * N_NODES * 8;
    for (int i = 0; i < 4; ++i) {
        int node = chunk * 16 + w * 4 + i;
        if (node >= N_NODES) return;
        int e0 = rp[node], e1 = rp[node + 1];
        float a0 = 0.f, a1 = 0.f;
        for (int e = e0 + sub; e < e1; e += 8) {
            unsigned u = fs[(size_t)colv[e] * 8 + c];
            a0 += bf2f((unsigned short)u); a1 += bf2f((unsigned short)(u >> 16));
        }
        a0 += __shfl_xor(a0, 8);  a1 += __shfl_xor(a1, 8);
        a0 += __shfl_xor(a0, 16); a1 += __shfl_xor(a1, 16);
        a0 += __shfl_xor(a0, 32); a1 += __shfl_xor(a1, 32);
        if (sub == 0) {
            unsigned su = fs[(size_t)node * 8 + c];
            a0 += bf2f((unsigned short)su); a1 += bf2f((unsigned short)(su >> 16));
            ts[(size_t)node * 8 + c] = (unsigned)f2bf(a0) | ((unsigned)f2bf(a1) << 16);
        }
    }
}

// ---------------- fused GIN MLP: h = relu(relu(t@w1+b1)@w2+b2), 64-node tile ----------------
// tin / hout are in sliced layout [8][N][16] bf16.
__global__ __launch_bounds__(256) void k_mlp(
    const unsigned short* __restrict__ tin,
    const unsigned short* __restrict__ w1t, const float* __restrict__ b1,
    const unsigned short* __restrict__ w2t, const float* __restrict__ b2,
    unsigned short* __restrict__ hout) {
    __shared__ __align__(16) char tlds[64 * 256];
    __shared__ __align__(16) char hlds[64 * 256];
    const int tid = threadIdx.x, lane = tid & 63, w = tid >> 6;
    const int l15 = lane & 15, lg = lane >> 4;
    const int nbase = blockIdx.x * 64;

    // stage t tile (swizzled); c8 chunk = 16B = half of a 32B slice row
    for (int i = 0; i < 4; ++i) {
        int idx = i * 256 + tid;
        int c8 = idx >> 6, r = idx & 63;           // consecutive tid -> consecutive nodes
        int slice = c8 >> 1, half = c8 & 1;
        int4 val{0, 0, 0, 0};
        int node = nbase + r;
        if (node < N_NODES)
            val = *(const int4*)(tin + ((size_t)slice * N_NODES + node) * 16 + half * 8);
        *(int4*)(tlds + r * 256 + ((c8 * 16) ^ ((r & 7) << 4))) = val;
    }

    // preload B1 fragments + bias (wave w owns out cols [32w, 32w+32))
    bf16x8 B1[2][4]; float bias1[2]; int cols[2];
    for (int ot = 0; ot < 2; ++ot) {
        int c = (w * 2 + ot) * 16 + l15;
        cols[ot] = c; bias1[ot] = b1[c];
        for (int ks = 0; ks < 4; ++ks)
            B1[ot][ks] = *(const bf16x8*)(w1t + (size_t)c * 128 + ks * 32 + lg * 8);
    }
    __syncthreads();

    // GEMM1 -> relu -> hlds
    for (int m = 0; m < 4; ++m) {
        bf16x8 A[4];
        for (int ks = 0; ks < 4; ++ks) {
            int row = m * 16 + l15;
            A[ks] = *(const bf16x8*)(tlds + row * 256 + ((ks * 64 + lg * 16) ^ ((row & 7) << 4)));
        }
        for (int ot = 0; ot < 2; ++ot) {
            f32x4 acc = {0.f, 0.f, 0.f, 0.f};
            for (int ks = 0; ks < 4; ++ks)
                acc = __builtin_amdgcn_mfma_f32_16x16x32_bf16(A[ks], B1[ot][ks], acc, 0, 0, 0);
            int c2 = cols[ot] * 2;
            for (int r = 0; r < 4; ++r) {
                int row = m * 16 + lg * 4 + r;
                float v = acc[r] + bias1[ot]; v = v > 0.f ? v : 0.f;
                *(unsigned short*)(hlds + row * 256 + (c2 ^ ((row & 7) << 4))) = f2bf(v);
            }
        }
    }

    // preload B2
    bf16x8 B2[2][4]; float bias2[2];
    for (int ot = 0; ot < 2; ++ot) {
        int c = cols[ot];
        bias2[ot] = b2[c];
        for (int ks = 0; ks < 4; ++ks)
            B2[ot][ks] = *(const bf16x8*)(w2t + (size_t)c * 128 + ks * 32 + lg * 8);
    }
    __syncthreads();

    // GEMM2 -> relu -> global (sliced layout)
    for (int m = 0; m < 4; ++m) {
        bf16x8 A[4];
        for (int ks = 0; ks < 4; ++ks) {
            int row = m * 16 + l15;
            A[ks] = *(const bf16x8*)(hlds + row * 256 + ((ks * 64 + lg * 16) ^ ((row & 7) << 4)));
        }
        for (int ot = 0; ot < 2; ++ot) {
            f32x4 acc = {0.f, 0.f, 0.f, 0.f};
            for (int ks = 0; ks < 4; ++ks)
                acc = __builtin_amdgcn_mfma_f32_16x16x32_bf16(A[ks], B2[ot][ks], acc, 0, 0, 0);
            int cslice = cols[ot] >> 4, cw = cols[ot] & 15;
            for (int r = 0; r < 4; ++r) {
                int node = nbase + m * 16 + lg * 4 + r;
                if (node < N_NODES) {
                    float v = acc[r] + bias2[ot]; v = v > 0.f ? v : 0.f;
                    hout[((size_t)cslice * N_NODES + node) * 16 + cw] = f2bf(v);
                }
            }
        }
    }
}

// ---------------- fused head: relu(concat@lin1+b) @ lin2 + b -> log_softmax ----------------
__global__ __launch_bounds__(256) void k_final(
    const unsigned short* __restrict__ h1, const unsigned short* __restrict__ h2,
    const unsigned short* __restrict__ h3,
    const unsigned short* __restrict__ l1t, const float* __restrict__ l1b,
    const unsigned short* __restrict__ l2t, const float* __restrict__ l2b,
    float* __restrict__ out) {
    __shared__ __align__(16) char lds[64 * 768];   // 48KB: A-tile then hidden
    const int tid = threadIdx.x, lane = tid & 63, w = tid >> 6;
    const int l15 = lane & 15, lg = lane >> 4;
    const int nbase = blockIdx.x * 64;

    // stage concat(h1,h2,h3) tile from sliced layouts, swizzled
    for (int i = 0; i < 12; ++i) {
        int idx = i * 256 + tid;
        int c8 = idx >> 6, r = idx & 63;           // c8 in [0,48)
        int part = c8 >> 4, c8p = c8 & 15;
        int slice = c8p >> 1, half = c8p & 1;
        const unsigned short* hp = part == 0 ? h1 : (part == 1 ? h2 : h3);
        int4 val{0, 0, 0, 0};
        int node = nbase + r;
        if (node < N_NODES)
            val = *(const int4*)(hp + ((size_t)slice * N_NODES + node) * 16 + half * 8);
        *(int4*)(lds + r * 768 + ((c8 * 16) ^ ((r & 7) << 4))) = val;
    }
    __syncthreads();

    // lin1: wave w owns out cols [96w, 96w+96)
    f32x4 acc[4][6];
    for (int m = 0; m < 4; ++m)
        for (int ot = 0; ot < 6; ++ot) acc[m][ot] = {0.f, 0.f, 0.f, 0.f};
    for (int ks = 0; ks < 12; ++ks) {
        bf16x8 A[4];
        for (int m = 0; m < 4; ++m) {
            int row = m * 16 + l15;
            A[m] = *(const bf16x8*)(lds + row * 768 + ((ks * 64 + lg * 16) ^ ((row & 7) << 4)));
        }
        for (int ot = 0; ot < 6; ++ot) {
            int c = (w * 6 + ot) * 16 + l15;
            bf16x8 B = *(const bf16x8*)(l1t + (size_t)c * 384 + ks * 32 + lg * 8);
            for (int m = 0; m < 4; ++m)
                acc[m][ot] = __builtin_amdgcn_mfma_f32_16x16x32_bf16(A[m], B, acc[m][ot], 0, 0, 0);
        }
    }
    __syncthreads();   // everyone done reading A-tile

    // relu + write hidden (bf16) into same LDS
    for (int ot = 0; ot < 6; ++ot) {
        int c = (w * 6 + ot) * 16 + l15;
        float bias = l1b[c];
        for (int m = 0; m < 4; ++m)
            for (int r = 0; r < 4; ++r) {
                int row = m * 16 + lg * 4 + r;
                float v = acc[m][ot][r] + bias; v = v > 0.f ? v : 0.f;
                *(unsigned short*)(lds + row * 768 + ((c * 2) ^ ((row & 7) << 4))) = f2bf(v);
            }
    }
    __syncthreads();

    // lin2: wave w owns rows [16w, 16w+16), 48 padded cols
    f32x4 acc2[3];
    for (int ot = 0; ot < 3; ++ot) acc2[ot] = {0.f, 0.f, 0.f, 0.f};
    for (int ks = 0; ks < 12; ++ks) {
        int row = w * 16 + l15;
        bf16x8 A = *(const bf16x8*)(lds + row * 768 + ((ks * 64 + lg * 16) ^ ((row & 7) << 4)));
        for (int ot = 0; ot < 3; ++ot) {
            int c = ot * 16 + l15;
            bf16x8 B = *(const bf16x8*)(l2t + (size_t)c * 384 + ks * 32 + lg * 8);
            acc2[ot] = __builtin_amdgcn_mfma_f32_16x16x32_bf16(A, B, acc2[ot], 0, 0, 0);
        }
    }

    // bias + log_softmax over 40 classes (row spread over 16 lanes x 3 regs)
    int c0 = l15;
    for (int r = 0; r < 4; ++r) {
        float v0 = acc2[0][r] + l2b[c0];
        float v1 = acc2[1][r] + l2b[c0 + 16];
        float v2 = (c0 < 8) ? (acc2[2][r] + l2b[c0 + 32]) : -1e30f;
        float mx = fmaxf(fmaxf(v0, v1), v2);
        for (int msk = 1; msk < 16; msk <<= 1) mx = fmaxf(mx, __shfl_xor(mx, msk));
        float s = __expf(v0 - mx) + __expf(v1 - mx) + ((c0 < 8) ? __expf(v2 - mx) : 0.f);
        for (int msk = 1; msk < 16; msk <<= 1) s += __shfl_xor(s, msk);
        float lse = mx + __logf(s);
        int node = nbase + w * 16 + lg * 4 + r;
        if (node < N_NODES) {
            out[(size_t)node * 40 + c0] = v0 - lse;
            out[(size_t)node * 40 + c0 + 16] = v1 - lse;
            if (c0 < 8) out[(size_t)node * 40 + c0 + 32] = v2 - lse;
        }
    }
}

extern "C" void kernel_launch(void* const* d_in, const int* in_sizes, int n_in,
                              void* d_out, int out_size, void* d_ws, size_t ws_size,
                              hipStream_t stream) {
    const float* x  = (const float*)d_in[0];
    const int*   ei = (const int*)d_in[1];
    const float* gw1[3] = {(const float*)d_in[2],  (const float*)d_in[6],  (const float*)d_in[10]};
    const float* gb1[3] = {(const float*)d_in[3],  (const float*)d_in[7],  (const float*)d_in[11]};
    const float* gw2[3] = {(const float*)d_in[4],  (const float*)d_in[8],  (const float*)d_in[12]};
    const float* gb2[3] = {(const float*)d_in[5],  (const float*)d_in[9],  (const float*)d_in[13]};
    const float* l1w = (const float*)d_in[14];
    const float* l1b = (const float*)d_in[15];
    const float* l2w = (const float*)d_in[16];
    const float* l2b = (const float*)d_in[17];
    float* out = (float*)d_out;

    char* p = (char*)d_ws;
    auto alloc = [&](size_t bytes) { char* q = p; p += (bytes + 255) & ~(size_t)255; return q; };
    int* rp   = (int*)alloc(4 * (N_NODES + 1));
    int* cnt  = (int*)alloc(4 * N_NODES);
    int* bsum = (int*)alloc(4 * 256);
    int* colv = (int*)alloc(4 * (size_t)NEDGE);
    unsigned short* t  = (unsigned short*)alloc(2 * (size_t)N_NODES * 128);
    unsigned short* h1 = (unsigned short*)alloc(2 * (size_t)N_NODES * 128);
    unsigned short* h2 = (unsigned short*)alloc(2 * (size_t)N_NODES * 128);
    unsigned short* h3 = (unsigned short*)alloc(2 * (size_t)N_NODES * 128);
    unsigned short* xs = h3;   // alias: xs dead after layer-1 agg, h3 written in layer 3
    unsigned short* wt[6];
    for (int i = 0; i < 6; ++i) wt[i] = (unsigned short*)alloc(2 * 128 * 128);
    unsigned short* l1t = (unsigned short*)alloc(2 * 384 * 384);
    unsigned short* l2t = (unsigned short*)alloc(2 * 48 * 384);

    const int nb = (N_NODES + 1023) / 1024;     // 98
    // CSR build
    k_zero<<<(N_NODES + 255) / 256, 256, 0, stream>>>(cnt, N_NODES);
    k_count<<<(NEDGE + 255) / 256, 256, 0, stream>>>(ei, cnt);
    k_scan1<<<nb, 256, 0, stream>>>(cnt, rp, bsum);
    k_scan2<<<1, 256, 0, stream>>>(bsum, nb);
    k_scan3<<<nb, 256, 0, stream>>>(rp, bsum);
    k_zero<<<(N_NODES + 255) / 256, 256, 0, stream>>>(cnt, N_NODES);
    k_fill<<<(NEDGE + 255) / 256, 256, 0, stream>>>(ei, rp, cnt, colv);

    // weight prep (transpose + bf16)
    for (int i = 0; i < 3; ++i) {
        k_wprep<<<(128 * 128 + 255) / 256, 256, 0, stream>>>(gw1[i], wt[2 * i], 128, 128, 128);
        k_wprep<<<(128 * 128 + 255) / 256, 256, 0, stream>>>(gw2[i], wt[2 * i + 1], 128, 128, 128);
    }
    k_wprep<<<(384 * 384 + 255) / 256, 256, 0, stream>>>(l1w, l1t, 384, 384, 384);
    k_wprep<<<(384 * 48 + 255) / 256, 256, 0, stream>>>(l2w, l2t, 384, 40, 48);

    // x -> sliced bf16
    k_xprep<<<8 * ((N_NODES * 8 + 255) / 256), 256, 0, stream>>>(x, xs);

    const int gagg = ((N_NODES + 15) / 16) * 8;
    const int gtile = (N_NODES + 63) / 64;
    // layer 1
    k_aggs<<<gagg, 256, 0, stream>>>(xs, t, rp, colv);
    k_mlp<<<gtile, 256, 0, stream>>>(t, wt[0], gb1[0], wt[1], gb2[0], h1);
    // layer 2
    k_aggs<<<gagg, 256, 0, stream>>>(h1, t, rp, colv);
    k_mlp<<<gtile, 256, 0, stream>>>(t, wt[2], gb1[1], wt[3], gb2[1], h2);
    // layer 3
    k_aggs<<<gagg, 256, 0, stream>>>(h2, t, rp, colv);
    k_mlp<<<gtile, 256, 0, stream>>>(t, wt[4], gb1[2], wt[5], gb2[2], h3);
    // head
    k_final<<<gtile, 256, 0, stream>>>(h1, h2, h3, l1t, l1b, l2t, l2b, out);
}

// Round 3
// 611.052 us; speedup vs baseline: 1.5607x; 1.5607x over previous
//
#include <hip/hip_runtime.h>

#define N_NODES 100000
#define NEDGE   1600000
#define NHID    128
#define NCLASS  40

#define AGG_NODES 128
#define COLV_LDS  3072

using bf16x8 = __attribute__((ext_vector_type(8))) short;
using f32x4  = __attribute__((ext_vector_type(4))) float;

__device__ __forceinline__ float bf2f(unsigned short s) {
    unsigned u = ((unsigned)s) << 16; float f; __builtin_memcpy(&f, &u, 4); return f;
}
__device__ __forceinline__ unsigned short f2bf(float f) {
    unsigned u; __builtin_memcpy(&u, &f, 4);
    u = u + 0x7fffu + ((u >> 16) & 1u);          // RNE
    return (unsigned short)(u >> 16);
}

// ---------------- CSR build ----------------
__global__ void k_zero(int* __restrict__ p, int n) {
    int i = blockIdx.x * 256 + threadIdx.x;
    if (i < n) p[i] = 0;
}

__global__ void k_count(const int* __restrict__ ei, int* __restrict__ cnt) {
    int e = blockIdx.x * 256 + threadIdx.x;
    if (e < NEDGE) atomicAdd(&cnt[ei[NEDGE + e]], 1);   // dst row of edge_index
}

// block scans 1024 elements (256 thr x 4)
__global__ void k_scan1(const int* __restrict__ cnt, int* __restrict__ rp, int* __restrict__ bsum) {
    __shared__ int sh[256];
    int t = threadIdx.x, base = blockIdx.x * 1024;
    int v[4]; int s = 0;
    for (int k = 0; k < 4; ++k) { int i = base + t * 4 + k; v[k] = (i < N_NODES) ? cnt[i] : 0; s += v[k]; }
    sh[t] = s; __syncthreads();
    for (int off = 1; off < 256; off <<= 1) {
        int x = (t >= off) ? sh[t - off] : 0;
        __syncthreads();
        sh[t] += x;
        __syncthreads();
    }
    int excl = sh[t] - s;
    for (int k = 0; k < 4; ++k) { int i = base + t * 4 + k; if (i < N_NODES) rp[i] = excl; excl += v[k]; }
    if (t == 255) bsum[blockIdx.x] = sh[255];
}

__global__ void k_scan2(int* __restrict__ bsum, int nb) {
    __shared__ int sh[256];
    int t = threadIdx.x;
    int v = (t < nb) ? bsum[t] : 0;
    sh[t] = v; __syncthreads();
    for (int off = 1; off < 256; off <<= 1) {
        int x = (t >= off) ? sh[t - off] : 0;
        __syncthreads();
        sh[t] += x;
        __syncthreads();
    }
    if (t < nb) bsum[t] = sh[t] - v;   // exclusive block offsets
}

__global__ void k_scan3(int* __restrict__ rp, const int* __restrict__ bsum) {
    int base = blockIdx.x * 1024;
    int off = bsum[blockIdx.x];
    for (int k = 0; k < 4; ++k) {
        int i = base + threadIdx.x * 4 + k;
        if (i < N_NODES) rp[i] += off;
    }
    if (blockIdx.x == 0 && threadIdx.x == 0) rp[N_NODES] = NEDGE;
}

__global__ void k_fill(const int* __restrict__ ei, const int* __restrict__ rp,
                       int* __restrict__ cur, int* __restrict__ colv) {
    int e = blockIdx.x * 256 + threadIdx.x;
    if (e < NEDGE) {
        int d = ei[NEDGE + e];
        int p = atomicAdd(&cur[d], 1);
        colv[rp[d] + p] = ei[e];
    }
}

// ---------------- weight prep: transpose + cvt to bf16, wt[o][k] = w[k][o] ----------------
__global__ void k_wprep(const float* __restrict__ w, unsigned short* __restrict__ wt,
                        int K, int O, int Opad) {
    int idx = blockIdx.x * 256 + threadIdx.x;
    if (idx >= K * Opad) return;
    int o = idx / K, k = idx - o * K;
    float v = (o < O) ? w[k * O + o] : 0.f;
    wt[idx] = f2bf(v);
}

// ---------------- x -> sliced bf16 layout [8][N][16] ----------------
__global__ void k_xprep(const float* __restrict__ x, unsigned short* __restrict__ xs) {
    int s = blockIdx.x & 7;
    int rest = (blockIdx.x >> 3) * 256 + threadIdx.x;   // word index within slice, N*8 words
    if (rest >= N_NODES * 8) return;
    int n = rest >> 3, wrd = rest & 7;
    float2 v = *(const float2*)(x + (size_t)n * 128 + s * 16 + wrd * 2);
    ((unsigned*)xs)[(size_t)s * N_NODES * 8 + rest] =
        (unsigned)f2bf(v.x) | ((unsigned)f2bf(v.y) << 16);
}

// ---------------- aggregation, sliced + LDS colv + 4-deep gather MLP ----------------
// slice = blockIdx & 7 -> XCD-pinned; per-XCD feature working set 3.2MB < 4MB L2.
// 2 lanes per node (16B each of the 32B slice row); 4 gathers in flight per sub.
__device__ __forceinline__ void acc8(float* acc, uint4 f, float m) {
    unsigned u[4] = {f.x, f.y, f.z, f.w};
    for (int d = 0; d < 4; ++d) {
        acc[2 * d]     = fmaf(m, bf2f((unsigned short)u[d]), acc[2 * d]);
        acc[2 * d + 1] = fmaf(m, bf2f((unsigned short)(u[d] >> 16)), acc[2 * d + 1]);
    }
}

__global__ __launch_bounds__(256) void k_aggs(const unsigned short* __restrict__ feat,
                                              unsigned short* __restrict__ tout,
                                              const int* __restrict__ rp,
                                              const int* __restrict__ colv) {
    __shared__ int scol[COLV_LDS];
    __shared__ int srp[AGG_NODES + 1];
    const int s = blockIdx.x & 7;
    const int chunk = blockIdx.x >> 3;
    const int tid = threadIdx.x;
    const int nbase = chunk * AGG_NODES;

    for (int i = tid; i <= AGG_NODES; i += 256) {
        int n = nbase + i;
        srp[i] = rp[n <= N_NODES ? n : N_NODES];
    }
    __syncthreads();
    const int ebase = srp[0];
    const int ecount = srp[AGG_NODES] - ebase;
    const int elds = ecount < COLV_LDS ? ecount : COLV_LDS;
    for (int i = tid; i < elds; i += 256) scol[i] = colv[ebase + i];
    __syncthreads();

    const unsigned* fs = (const unsigned*)feat + (size_t)s * N_NODES * 8;
    unsigned* ts = (unsigned*)tout + (size_t)s * N_NODES * 8;

    const int sub = tid >> 1, half = tid & 1;
    const int node = nbase + sub;
    if (node >= N_NODES) return;
    const int off = half * 4;
    const int e0 = srp[sub] - ebase, e1 = srp[sub + 1] - ebase;

    float acc[8];
    {
        uint4 a = *(const uint4*)(fs + (size_t)node * 8 + off);
        unsigned u[4] = {a.x, a.y, a.z, a.w};
        for (int d = 0; d < 4; ++d) {
            acc[2 * d]     = bf2f((unsigned short)u[d]);
            acc[2 * d + 1] = bf2f((unsigned short)(u[d] >> 16));
        }
    }

    for (int e = e0; e < e1; e += 4) {
        int j[4]; float m[4];
        #pragma unroll
        for (int k = 0; k < 4; ++k) {
            int ee = e + k;
            bool v = ee < e1;
            int idx = ee < COLV_LDS ? scol[ee] : colv[ebase + ee];
            j[k] = v ? idx : node;
            m[k] = v ? 1.f : 0.f;
        }
        uint4 f[4];
        #pragma unroll
        for (int k = 0; k < 4; ++k)
            f[k] = *(const uint4*)(fs + (size_t)j[k] * 8 + off);
        #pragma unroll
        for (int k = 0; k < 4; ++k) acc8(acc, f[k], m[k]);
    }

    uint4 o;
    o.x = (unsigned)f2bf(acc[0]) | ((unsigned)f2bf(acc[1]) << 16);
    o.y = (unsigned)f2bf(acc[2]) | ((unsigned)f2bf(acc[3]) << 16);
    o.z = (unsigned)f2bf(acc[4]) | ((unsigned)f2bf(acc[5]) << 16);
    o.w = (unsigned)f2bf(acc[6]) | ((unsigned)f2bf(acc[7]) << 16);
    *(uint4*)(ts + (size_t)node * 8 + off) = o;
}

// ---------------- fused GIN MLP: h = relu(relu(t@w1+b1)@w2+b2), 64-node tile ----------------
// tin / hout are in sliced layout [8][N][16] bf16.
__global__ __launch_bounds__(256) void k_mlp(
    const unsigned short* __restrict__ tin,
    const unsigned short* __restrict__ w1t, const float* __restrict__ b1,
    const unsigned short* __restrict__ w2t, const float* __restrict__ b2,
    unsigned short* __restrict__ hout) {
    __shared__ __align__(16) char tlds[64 * 256];
    __shared__ __align__(16) char hlds[64 * 256];
    const int tid = threadIdx.x, lane = tid & 63, w = tid >> 6;
    const int l15 = lane & 15, lg = lane >> 4;
    const int nbase = blockIdx.x * 64;

    // stage t tile (swizzled); c8 chunk = 16B = half of a 32B slice row
    for (int i = 0; i < 4; ++i) {
        int idx = i * 256 + tid;
        int c8 = idx >> 6, r = idx & 63;           // consecutive tid -> consecutive nodes
        int slice = c8 >> 1, half = c8 & 1;
        int4 val{0, 0, 0, 0};
        int node = nbase + r;
        if (node < N_NODES)
            val = *(const int4*)(tin + ((size_t)slice * N_NODES + node) * 16 + half * 8);
        *(int4*)(tlds + r * 256 + ((c8 * 16) ^ ((r & 7) << 4))) = val;
    }

    // preload B1 fragments + bias (wave w owns out cols [32w, 32w+32))
    bf16x8 B1[2][4]; float bias1[2]; int cols[2];
    for (int ot = 0; ot < 2; ++ot) {
        int c = (w * 2 + ot) * 16 + l15;
        cols[ot] = c; bias1[ot] = b1[c];
        for (int ks = 0; ks < 4; ++ks)
            B1[ot][ks] = *(const bf16x8*)(w1t + (size_t)c * 128 + ks * 32 + lg * 8);
    }
    __syncthreads();

    // GEMM1 -> relu -> hlds
    for (int m = 0; m < 4; ++m) {
        bf16x8 A[4];
        for (int ks = 0; ks < 4; ++ks) {
            int row = m * 16 + l15;
            A[ks] = *(const bf16x8*)(tlds + row * 256 + ((ks * 64 + lg * 16) ^ ((row & 7) << 4)));
        }
        for (int ot = 0; ot < 2; ++ot) {
            f32x4 acc = {0.f, 0.f, 0.f, 0.f};
            for (int ks = 0; ks < 4; ++ks)
                acc = __builtin_amdgcn_mfma_f32_16x16x32_bf16(A[ks], B1[ot][ks], acc, 0, 0, 0);
            int c2 = cols[ot] * 2;
            for (int r = 0; r < 4; ++r) {
                int row = m * 16 + lg * 4 + r;
                float v = acc[r] + bias1[ot]; v = v > 0.f ? v : 0.f;
                *(unsigned short*)(hlds + row * 256 + (c2 ^ ((row & 7) << 4))) = f2bf(v);
            }
        }
    }

    // preload B2
    bf16x8 B2[2][4]; float bias2[2];
    for (int ot = 0; ot < 2; ++ot) {
        int c = cols[ot];
        bias2[ot] = b2[c];
        for (int ks = 0; ks < 4; ++ks)
            B2[ot][ks] = *(const bf16x8*)(w2t + (size_t)c * 128 + ks * 32 + lg * 8);
    }
    __syncthreads();

    // GEMM2 -> relu -> global (sliced layout)
    for (int m = 0; m < 4; ++m) {
        bf16x8 A[4];
        for (int ks = 0; ks < 4; ++ks) {
            int row = m * 16 + l15;
            A[ks] = *(const bf16x8*)(hlds + row * 256 + ((ks * 64 + lg * 16) ^ ((row & 7) << 4)));
        }
        for (int ot = 0; ot < 2; ++ot) {
            f32x4 acc = {0.f, 0.f, 0.f, 0.f};
            for (int ks = 0; ks < 4; ++ks)
                acc = __builtin_amdgcn_mfma_f32_16x16x32_bf16(A[ks], B2[ot][ks], acc, 0, 0, 0);
            int cslice = cols[ot] >> 4, cw = cols[ot] & 15;
            for (int r = 0; r < 4; ++r) {
                int node = nbase + m * 16 + lg * 4 + r;
                if (node < N_NODES) {
                    float v = acc[r] + bias2[ot]; v = v > 0.f ? v : 0.f;
                    hout[((size_t)cslice * N_NODES + node) * 16 + cw] = f2bf(v);
                }
            }
        }
    }
}

// ---------------- fused head: relu(concat@lin1+b) @ lin2 + b -> log_softmax ----------------
__global__ __launch_bounds__(256) void k_final(
    const unsigned short* __restrict__ h1, const unsigned short* __restrict__ h2,
    const unsigned short* __restrict__ h3,
    const unsigned short* __restrict__ l1t, const float* __restrict__ l1b,
    const unsigned short* __restrict__ l2t, const float* __restrict__ l2b,
    float* __restrict__ out) {
    __shared__ __align__(16) char lds[64 * 768];   // 48KB: A-tile then hidden
    const int tid = threadIdx.x, lane = tid & 63, w = tid >> 6;
    const int l15 = lane & 15, lg = lane >> 4;
    const int nbase = blockIdx.x * 64;

    // stage concat(h1,h2,h3) tile from sliced layouts, swizzled
    for (int i = 0; i < 12; ++i) {
        int idx = i * 256 + tid;
        int c8 = idx >> 6, r = idx & 63;           // c8 in [0,48)
        int part = c8 >> 4, c8p = c8 & 15;
        int slice = c8p >> 1, half = c8p & 1;
        const unsigned short* hp = part == 0 ? h1 : (part == 1 ? h2 : h3);
        int4 val{0, 0, 0, 0};
        int node = nbase + r;
        if (node < N_NODES)
            val = *(const int4*)(hp + ((size_t)slice * N_NODES + node) * 16 + half * 8);
        *(int4*)(lds + r * 768 + ((c8 * 16) ^ ((r & 7) << 4))) = val;
    }
    __syncthreads();

    // lin1: wave w owns out cols [96w, 96w+96)
    f32x4 acc[4][6];
    for (int m = 0; m < 4; ++m)
        for (int ot = 0; ot < 6; ++ot) acc[m][ot] = {0.f, 0.f, 0.f, 0.f};
    for (int ks = 0; ks < 12; ++ks) {
        bf16x8 A[4];
        for (int m = 0; m < 4; ++m) {
            int row = m * 16 + l15;
            A[m] = *(const bf16x8*)(lds + row * 768 + ((ks * 64 + lg * 16) ^ ((row & 7) << 4)));
        }
        for (int ot = 0; ot < 6; ++ot) {
            int c = (w * 6 + ot) * 16 + l15;
            bf16x8 B = *(const bf16x8*)(l1t + (size_t)c * 384 + ks * 32 + lg * 8);
            for (int m = 0; m < 4; ++m)
                acc[m][ot] = __builtin_amdgcn_mfma_f32_16x16x32_bf16(A[m], B, acc[m][ot], 0, 0, 0);
        }
    }
    __syncthreads();   // everyone done reading A-tile

    // relu + write hidden (bf16) into same LDS
    for (int ot = 0; ot < 6; ++ot) {
        int c = (w * 6 + ot) * 16 + l15;
        float bias = l1b[c];
        for (int m = 0; m < 4; ++m)
            for (int r = 0; r < 4; ++r) {
                int row = m * 16 + lg * 4 + r;
                float v = acc[m][ot][r] + bias; v = v > 0.f ? v : 0.f;
                *(unsigned short*)(lds + row * 768 + ((c * 2) ^ ((row & 7) << 4))) = f2bf(v);
            }
    }
    __syncthreads();

    // lin2: wave w owns rows [16w, 16w+16), 48 padded cols
    f32x4 acc2[3];
    for (int ot = 0; ot < 3; ++ot) acc2[ot] = {0.f, 0.f, 0.f, 0.f};
    for (int ks = 0; ks < 12; ++ks) {
        int row = w * 16 + l15;
        bf16x8 A = *(const bf16x8*)(lds + row * 768 + ((ks * 64 + lg * 16) ^ ((row & 7) << 4)));
        for (int ot = 0; ot < 3; ++ot) {
            int c = ot * 16 + l15;
            bf16x8 B = *(const bf16x8*)(l2t + (size_t)c * 384 + ks * 32 + lg * 8);
            acc2[ot] = __builtin_amdgcn_mfma_f32_16x16x32_bf16(A, B, acc2[ot], 0, 0, 0);
        }
    }

    // bias + log_softmax over 40 classes (row spread over 16 lanes x 3 regs)
    int c0 = l15;
    for (int r = 0; r < 4; ++r) {
        float v0 = acc2[0][r] + l2b[c0];
        float v1 = acc2[1][r] + l2b[c0 + 16];
        float v2 = (c0 < 8) ? (acc2[2][r] + l2b[c0 + 32]) : -1e30f;
        float mx = fmaxf(fmaxf(v0, v1), v2);
        for (int msk = 1; msk < 16; msk <<= 1) mx = fmaxf(mx, __shfl_xor(mx, msk));
        float s = __expf(v0 - mx) + __expf(v1 - mx) + ((c0 < 8) ? __expf(v2 - mx) : 0.f);
        for (int msk = 1; msk < 16; msk <<= 1) s += __shfl_xor(s, msk);
        float lse = mx + __logf(s);
        int node = nbase + w * 16 + lg * 4 + r;
        if (node < N_NODES) {
            out[(size_t)node * 40 + c0] = v0 - lse;
            out[(size_t)node * 40 + c0 + 16] = v1 - lse;
            if (c0 < 8) out[(size_t)node * 40 + c0 + 32] = v2 - lse;
        }
    }
}

extern "C" void kernel_launch(void* const* d_in, const int* in_sizes, int n_in,
                              void* d_out, int out_size, void* d_ws, size_t ws_size,
                              hipStream_t stream) {
    const float* x  = (const float*)d_in[0];
    const int*   ei = (const int*)d_in[1];
    const float* gw1[3] = {(const float*)d_in[2],  (const float*)d_in[6],  (const float*)d_in[10]};
    const float* gb1[3] = {(const float*)d_in[3],  (const float*)d_in[7],  (const float*)d_in[11]};
    const float* gw2[3] = {(const float*)d_in[4],  (const float*)d_in[8],  (const float*)d_in[12]};
    const float* gb2[3] = {(const float*)d_in[5],  (const float*)d_in[9],  (const float*)d_in[13]};
    const float* l1w = (const float*)d_in[14];
    const float* l1b = (const float*)d_in[15];
    const float* l2w = (const float*)d_in[16];
    const float* l2b = (const float*)d_in[17];
    float* out = (float*)d_out;

    char* p = (char*)d_ws;
    auto alloc = [&](size_t bytes) { char* q = p; p += (bytes + 255) & ~(size_t)255; return q; };
    int* rp   = (int*)alloc(4 * (N_NODES + 1));
    int* cnt  = (int*)alloc(4 * N_NODES);
    int* bsum = (int*)alloc(4 * 256);
    int* colv = (int*)alloc(4 * (size_t)NEDGE);
    unsigned short* t  = (unsigned short*)alloc(2 * (size_t)N_NODES * 128);
    unsigned short* h1 = (unsigned short*)alloc(2 * (size_t)N_NODES * 128);
    unsigned short* h2 = (unsigned short*)alloc(2 * (size_t)N_NODES * 128);
    unsigned short* h3 = (unsigned short*)alloc(2 * (size_t)N_NODES * 128);
    unsigned short* xs = h3;   // alias: xs dead after layer-1 agg, h3 written in layer 3
    unsigned short* wt[6];
    for (int i = 0; i < 6; ++i) wt[i] = (unsigned short*)alloc(2 * 128 * 128);
    unsigned short* l1t = (unsigned short*)alloc(2 * 384 * 384);
    unsigned short* l2t = (unsigned short*)alloc(2 * 48 * 384);

    const int nb = (N_NODES + 1023) / 1024;     // 98
    // CSR build
    k_zero<<<(N_NODES + 255) / 256, 256, 0, stream>>>(cnt, N_NODES);
    k_count<<<(NEDGE + 255) / 256, 256, 0, stream>>>(ei, cnt);
    k_scan1<<<nb, 256, 0, stream>>>(cnt, rp, bsum);
    k_scan2<<<1, 256, 0, stream>>>(bsum, nb);
    k_scan3<<<nb, 256, 0, stream>>>(rp, bsum);
    k_zero<<<(N_NODES + 255) / 256, 256, 0, stream>>>(cnt, N_NODES);
    k_fill<<<(NEDGE + 255) / 256, 256, 0, stream>>>(ei, rp, cnt, colv);

    // weight prep (transpose + bf16)
    for (int i = 0; i < 3; ++i) {
        k_wprep<<<(128 * 128 + 255) / 256, 256, 0, stream>>>(gw1[i], wt[2 * i], 128, 128, 128);
        k_wprep<<<(128 * 128 + 255) / 256, 256, 0, stream>>>(gw2[i], wt[2 * i + 1], 128, 128, 128);
    }
    k_wprep<<<(384 * 384 + 255) / 256, 256, 0, stream>>>(l1w, l1t, 384, 384, 384);
    k_wprep<<<(384 * 48 + 255) / 256, 256, 0, stream>>>(l2w, l2t, 384, 40, 48);

    // x -> sliced bf16
    k_xprep<<<8 * ((N_NODES * 8 + 255) / 256), 256, 0, stream>>>(x, xs);

    const int gagg = ((N_NODES + AGG_NODES - 1) / AGG_NODES) * 8;
    const int gtile = (N_NODES + 63) / 64;
    // layer 1
    k_aggs<<<gagg, 256, 0, stream>>>(xs, t, rp, colv);
    k_mlp<<<gtile, 256, 0, stream>>>(t, wt[0], gb1[0], wt[1], gb2[0], h1);
    // layer 2
    k_aggs<<<gagg, 256, 0, stream>>>(h1, t, rp, colv);
    k_mlp<<<gtile, 256, 0, stream>>>(t, wt[2], gb1[1], wt[3], gb2[1], h2);
    // layer 3
    k_aggs<<<gagg, 256, 0, stream>>>(h2, t, rp, colv);
    k_mlp<<<gtile, 256, 0, stream>>>(t, wt[4], gb1[2], wt[5], gb2[2], h3);
    // head
    k_final<<<gtile, 256, 0, stream>>>(h1, h2, h3, l1t, l1b, l2t, l2b, out);
}

// Round 4
// 593.649 us; speedup vs baseline: 1.6065x; 1.0293x over previous
//
#include <hip/hip_runtime.h>

#define N_NODES 100000
#define NEDGE   1600000
#define NHID    128
#define NCLASS  40

#define AGG_NODES 128
#define COLV_LDS  3072

using bf16x8 = __attribute__((ext_vector_type(8))) short;
using f32x4  = __attribute__((ext_vector_type(4))) float;

__device__ __forceinline__ float bf2f(unsigned short s) {
    unsigned u = ((unsigned)s) << 16; float f; __builtin_memcpy(&f, &u, 4); return f;
}
__device__ __forceinline__ unsigned short f2bf(float f) {
    unsigned u; __builtin_memcpy(&u, &f, 4);
    u = u + 0x7fffu + ((u >> 16) & 1u);          // RNE
    return (unsigned short)(u >> 16);
}

// ---------------- CSR build ----------------
__global__ void k_zero(int* __restrict__ p, int n) {
    int i = blockIdx.x * 256 + threadIdx.x;
    if (i < n) p[i] = 0;
}

__global__ void k_count(const int* __restrict__ ei, int* __restrict__ cnt) {
    int e = blockIdx.x * 256 + threadIdx.x;
    if (e < NEDGE) atomicAdd(&cnt[ei[NEDGE + e]], 1);   // dst row of edge_index
}

// block scans 1024 elements (256 thr x 4)
__global__ void k_scan1(const int* __restrict__ cnt, int* __restrict__ rp, int* __restrict__ bsum) {
    __shared__ int sh[256];
    int t = threadIdx.x, base = blockIdx.x * 1024;
    int v[4]; int s = 0;
    for (int k = 0; k < 4; ++k) { int i = base + t * 4 + k; v[k] = (i < N_NODES) ? cnt[i] : 0; s += v[k]; }
    sh[t] = s; __syncthreads();
    for (int off = 1; off < 256; off <<= 1) {
        int x = (t >= off) ? sh[t - off] : 0;
        __syncthreads();
        sh[t] += x;
        __syncthreads();
    }
    int excl = sh[t] - s;
    for (int k = 0; k < 4; ++k) { int i = base + t * 4 + k; if (i < N_NODES) rp[i] = excl; excl += v[k]; }
    if (t == 255) bsum[blockIdx.x] = sh[255];
}

__global__ void k_scan2(int* __restrict__ bsum, int nb) {
    __shared__ int sh[256];
    int t = threadIdx.x;
    int v = (t < nb) ? bsum[t] : 0;
    sh[t] = v; __syncthreads();
    for (int off = 1; off < 256; off <<= 1) {
        int x = (t >= off) ? sh[t - off] : 0;
        __syncthreads();
        sh[t] += x;
        __syncthreads();
    }
    if (t < nb) bsum[t] = sh[t] - v;   // exclusive block offsets
}

__global__ void k_scan3(int* __restrict__ rp, const int* __restrict__ bsum) {
    int base = blockIdx.x * 1024;
    int off = bsum[blockIdx.x];
    for (int k = 0; k < 4; ++k) {
        int i = base + threadIdx.x * 4 + k;
        if (i < N_NODES) rp[i] += off;
    }
    if (blockIdx.x == 0 && threadIdx.x == 0) rp[N_NODES] = NEDGE;
}

__global__ void k_fill(const int* __restrict__ ei, const int* __restrict__ rp,
                       int* __restrict__ cur, int* __restrict__ colv) {
    int e = blockIdx.x * 256 + threadIdx.x;
    if (e < NEDGE) {
        int d = ei[NEDGE + e];
        int p = atomicAdd(&cur[d], 1);
        colv[rp[d] + p] = ei[e];
    }
}

// ---------------- weight prep: fragment-major bf16 layout ----------------
// wt[((ot*KS + ks)*64 + lane)*8 + e] = w[k][c],  c = ot*16 + (lane&15),
// k = ks*32 + (lane>>4)*8 + e.  One B-fragment load = 64 lanes x contiguous 16B.
__global__ void k_wprep(const float* __restrict__ w, unsigned short* __restrict__ wt,
                        int K, int O, int Opad) {
    int idx = blockIdx.x * 256 + threadIdx.x;
    if (idx >= K * Opad) return;
    int kss = K >> 5;
    int e = idx & 7, lane = (idx >> 3) & 63, rest = idx >> 9;
    int ks = rest % kss, ot = rest / kss;
    int c = ot * 16 + (lane & 15);
    int k = ks * 32 + (lane >> 4) * 8 + e;
    float v = (c < O) ? w[k * O + c] : 0.f;
    wt[idx] = f2bf(v);
}

// ---------------- x -> sliced bf16 layout [8][N][16] ----------------
__global__ void k_xprep(const float* __restrict__ x, unsigned short* __restrict__ xs) {
    int s = blockIdx.x & 7;
    int rest = (blockIdx.x >> 3) * 256 + threadIdx.x;   // word index within slice, N*8 words
    if (rest >= N_NODES * 8) return;
    int n = rest >> 3, wrd = rest & 7;
    float2 v = *(const float2*)(x + (size_t)n * 128 + s * 16 + wrd * 2);
    ((unsigned*)xs)[(size_t)s * N_NODES * 8 + rest] =
        (unsigned)f2bf(v.x) | ((unsigned)f2bf(v.y) << 16);
}

// ---------------- aggregation, sliced + LDS colv + 4-deep gather MLP ----------------
__device__ __forceinline__ void acc8(float* acc, uint4 f, float m) {
    unsigned u[4] = {f.x, f.y, f.z, f.w};
    for (int d = 0; d < 4; ++d) {
        acc[2 * d]     = fmaf(m, bf2f((unsigned short)u[d]), acc[2 * d]);
        acc[2 * d + 1] = fmaf(m, bf2f((unsigned short)(u[d] >> 16)), acc[2 * d + 1]);
    }
}

__global__ __launch_bounds__(256) void k_aggs(const unsigned short* __restrict__ feat,
                                              unsigned short* __restrict__ tout,
                                              const int* __restrict__ rp,
                                              const int* __restrict__ colv) {
    __shared__ int scol[COLV_LDS];
    __shared__ int srp[AGG_NODES + 1];
    const int s = blockIdx.x & 7;
    const int chunk = blockIdx.x >> 3;
    const int tid = threadIdx.x;
    const int nbase = chunk * AGG_NODES;

    for (int i = tid; i <= AGG_NODES; i += 256) {
        int n = nbase + i;
        srp[i] = rp[n <= N_NODES ? n : N_NODES];
    }
    __syncthreads();
    const int ebase = srp[0];
    const int ecount = srp[AGG_NODES] - ebase;
    const int elds = ecount < COLV_LDS ? ecount : COLV_LDS;
    for (int i = tid; i < elds; i += 256) scol[i] = colv[ebase + i];
    __syncthreads();

    const unsigned* fs = (const unsigned*)feat + (size_t)s * N_NODES * 8;
    unsigned* ts = (unsigned*)tout + (size_t)s * N_NODES * 8;

    const int sub = tid >> 1, half = tid & 1;
    const int node = nbase + sub;
    if (node >= N_NODES) return;
    const int off = half * 4;
    const int e0 = srp[sub] - ebase, e1 = srp[sub + 1] - ebase;

    float acc[8];
    {
        uint4 a = *(const uint4*)(fs + (size_t)node * 8 + off);
        unsigned u[4] = {a.x, a.y, a.z, a.w};
        for (int d = 0; d < 4; ++d) {
            acc[2 * d]     = bf2f((unsigned short)u[d]);
            acc[2 * d + 1] = bf2f((unsigned short)(u[d] >> 16));
        }
    }

    for (int e = e0; e < e1; e += 4) {
        int j[4]; float m[4];
        #pragma unroll
        for (int k = 0; k < 4; ++k) {
            int ee = e + k;
            bool v = ee < e1;
            int idx = ee < COLV_LDS ? scol[ee] : colv[ebase + ee];
            j[k] = v ? idx : node;
            m[k] = v ? 1.f : 0.f;
        }
        uint4 f[4];
        #pragma unroll
        for (int k = 0; k < 4; ++k)
            f[k] = *(const uint4*)(fs + (size_t)j[k] * 8 + off);
        #pragma unroll
        for (int k = 0; k < 4; ++k) acc8(acc, f[k], m[k]);
    }

    uint4 o;
    o.x = (unsigned)f2bf(acc[0]) | ((unsigned)f2bf(acc[1]) << 16);
    o.y = (unsigned)f2bf(acc[2]) | ((unsigned)f2bf(acc[3]) << 16);
    o.z = (unsigned)f2bf(acc[4]) | ((unsigned)f2bf(acc[5]) << 16);
    o.w = (unsigned)f2bf(acc[6]) | ((unsigned)f2bf(acc[7]) << 16);
    *(uint4*)(ts + (size_t)node * 8 + off) = o;
}

// ---------------- fused GIN MLP: h = relu(relu(t@w1+b1)@w2+b2), 64-node tile ----------------
// tin / hout sliced [8][N][16] bf16; w1t/w2t fragment-major (KS=4, 8 ot-tiles).
__global__ __launch_bounds__(256) void k_mlp(
    const unsigned short* __restrict__ tin,
    const unsigned short* __restrict__ w1t, const float* __restrict__ b1,
    const unsigned short* __restrict__ w2t, const float* __restrict__ b2,
    unsigned short* __restrict__ hout) {
    __shared__ __align__(16) char tlds[64 * 256];
    __shared__ __align__(16) char hlds[64 * 256];
    const int tid = threadIdx.x, lane = tid & 63, w = tid >> 6;
    const int l15 = lane & 15, lg = lane >> 4;
    const int nbase = blockIdx.x * 64;

    // stage t tile (swizzled); c8 chunk = 16B = half of a 32B slice row
    for (int i = 0; i < 4; ++i) {
        int idx = i * 256 + tid;
        int c8 = idx >> 6, r = idx & 63;           // consecutive tid -> consecutive nodes
        int slice = c8 >> 1, half = c8 & 1;
        int4 val{0, 0, 0, 0};
        int node = nbase + r;
        if (node < N_NODES)
            val = *(const int4*)(tin + ((size_t)slice * N_NODES + node) * 16 + half * 8);
        *(int4*)(tlds + r * 256 + ((c8 * 16) ^ ((r & 7) << 4))) = val;
    }

    // preload B1 fragments + bias (wave w owns out cols [32w, 32w+32))
    bf16x8 B1[2][4]; float bias1[2]; int cols[2];
    for (int ot = 0; ot < 2; ++ot) {
        int c = (w * 2 + ot) * 16 + l15;
        cols[ot] = c; bias1[ot] = b1[c];
        for (int ks = 0; ks < 4; ++ks)
            B1[ot][ks] = *(const bf16x8*)(w1t + ((size_t)((w * 2 + ot) * 4 + ks) * 64 + lane) * 8);
    }
    __syncthreads();

    // GEMM1 -> relu -> hlds
    for (int m = 0; m < 4; ++m) {
        bf16x8 A[4];
        for (int ks = 0; ks < 4; ++ks) {
            int row = m * 16 + l15;
            A[ks] = *(const bf16x8*)(tlds + row * 256 + ((ks * 64 + lg * 16) ^ ((row & 7) << 4)));
        }
        for (int ot = 0; ot < 2; ++ot) {
            f32x4 acc = {0.f, 0.f, 0.f, 0.f};
            for (int ks = 0; ks < 4; ++ks)
                acc = __builtin_amdgcn_mfma_f32_16x16x32_bf16(A[ks], B1[ot][ks], acc, 0, 0, 0);
            int c2 = cols[ot] * 2;
            for (int r = 0; r < 4; ++r) {
                int row = m * 16 + lg * 4 + r;
                float v = acc[r] + bias1[ot]; v = v > 0.f ? v : 0.f;
                *(unsigned short*)(hlds + row * 256 + (c2 ^ ((row & 7) << 4))) = f2bf(v);
            }
        }
    }

    // preload B2
    bf16x8 B2[2][4]; float bias2[2];
    for (int ot = 0; ot < 2; ++ot) {
        bias2[ot] = b2[cols[ot]];
        for (int ks = 0; ks < 4; ++ks)
            B2[ot][ks] = *(const bf16x8*)(w2t + ((size_t)((w * 2 + ot) * 4 + ks) * 64 + lane) * 8);
    }
    __syncthreads();

    // GEMM2 -> relu -> global (sliced layout)
    for (int m = 0; m < 4; ++m) {
        bf16x8 A[4];
        for (int ks = 0; ks < 4; ++ks) {
            int row = m * 16 + l15;
            A[ks] = *(const bf16x8*)(hlds + row * 256 + ((ks * 64 + lg * 16) ^ ((row & 7) << 4)));
        }
        for (int ot = 0; ot < 2; ++ot) {
            f32x4 acc = {0.f, 0.f, 0.f, 0.f};
            for (int ks = 0; ks < 4; ++ks)
                acc = __builtin_amdgcn_mfma_f32_16x16x32_bf16(A[ks], B2[ot][ks], acc, 0, 0, 0);
            int cslice = cols[ot] >> 4, cw = cols[ot] & 15;
            for (int r = 0; r < 4; ++r) {
                int node = nbase + m * 16 + lg * 4 + r;
                if (node < N_NODES) {
                    float v = acc[r] + bias2[ot]; v = v > 0.f ? v : 0.f;
                    hout[((size_t)cslice * N_NODES + node) * 16 + cw] = f2bf(v);
                }
            }
        }
    }
}

// ---------------- fused head: relu(concat@lin1+b) @ lin2 + b -> log_softmax ----------------
// l1t fragment-major (KS=12, 24 ot); l2t fragment-major (KS=12, 3 ot, cols padded to 48).
__global__ __launch_bounds__(256) void k_final(
    const unsigned short* __restrict__ h1, const unsigned short* __restrict__ h2,
    const unsigned short* __restrict__ h3,
    const unsigned short* __restrict__ l1t, const float* __restrict__ l1b,
    const unsigned short* __restrict__ l2t, const float* __restrict__ l2b,
    float* __restrict__ out) {
    __shared__ __align__(16) char lds[64 * 768];   // 48KB: A-tile then hidden
    const int tid = threadIdx.x, lane = tid & 63, w = tid >> 6;
    const int l15 = lane & 15, lg = lane >> 4;
    const int nbase = blockIdx.x * 64;

    // stage concat(h1,h2,h3) tile from sliced layouts, swizzled
    for (int i = 0; i < 12; ++i) {
        int idx = i * 256 + tid;
        int c8 = idx >> 6, r = idx & 63;           // c8 in [0,48)
        int part = c8 >> 4, c8p = c8 & 15;
        int slice = c8p >> 1, half = c8p & 1;
        const unsigned short* hp = part == 0 ? h1 : (part == 1 ? h2 : h3);
        int4 val{0, 0, 0, 0};
        int node = nbase + r;
        if (node < N_NODES)
            val = *(const int4*)(hp + ((size_t)slice * N_NODES + node) * 16 + half * 8);
        *(int4*)(lds + r * 768 + ((c8 * 16) ^ ((r & 7) << 4))) = val;
    }
    __syncthreads();

    // lin1: wave w owns out cols [96w, 96w+96)
    f32x4 acc[4][6];
    for (int m = 0; m < 4; ++m)
        for (int ot = 0; ot < 6; ++ot) acc[m][ot] = {0.f, 0.f, 0.f, 0.f};
    for (int ks = 0; ks < 12; ++ks) {
        bf16x8 A[4];
        for (int m = 0; m < 4; ++m) {
            int row = m * 16 + l15;
            A[m] = *(const bf16x8*)(lds + row * 768 + ((ks * 64 + lg * 16) ^ ((row & 7) << 4)));
        }
        for (int ot = 0; ot < 6; ++ot) {
            bf16x8 B = *(const bf16x8*)(l1t + ((size_t)((w * 6 + ot) * 12 + ks) * 64 + lane) * 8);
            for (int m = 0; m < 4; ++m)
                acc[m][ot] = __builtin_amdgcn_mfma_f32_16x16x32_bf16(A[m], B, acc[m][ot], 0, 0, 0);
        }
    }
    __syncthreads();   // everyone done reading A-tile

    // relu + write hidden (bf16) into same LDS
    for (int ot = 0; ot < 6; ++ot) {
        int c = (w * 6 + ot) * 16 + l15;
        float bias = l1b[c];
        for (int m = 0; m < 4; ++m)
            for (int r = 0; r < 4; ++r) {
                int row = m * 16 + lg * 4 + r;
                float v = acc[m][ot][r] + bias; v = v > 0.f ? v : 0.f;
                *(unsigned short*)(lds + row * 768 + ((c * 2) ^ ((row & 7) << 4))) = f2bf(v);
            }
    }
    __syncthreads();

    // lin2: wave w owns rows [16w, 16w+16), 48 padded cols
    f32x4 acc2[3];
    for (int ot = 0; ot < 3; ++ot) acc2[ot] = {0.f, 0.f, 0.f, 0.f};
    for (int ks = 0; ks < 12; ++ks) {
        int row = w * 16 + l15;
        bf16x8 A = *(const bf16x8*)(lds + row * 768 + ((ks * 64 + lg * 16) ^ ((row & 7) << 4)));
        for (int ot = 0; ot < 3; ++ot) {
            bf16x8 B = *(const bf16x8*)(l2t + ((size_t)(ot * 12 + ks) * 64 + lane) * 8);
            acc2[ot] = __builtin_amdgcn_mfma_f32_16x16x32_bf16(A, B, acc2[ot], 0, 0, 0);
        }
    }

    // bias + log_softmax over 40 classes (row spread over 16 lanes x 3 regs)
    int c0 = l15;
    for (int r = 0; r < 4; ++r) {
        float v0 = acc2[0][r] + l2b[c0];
        float v1 = acc2[1][r] + l2b[c0 + 16];
        float v2 = (c0 < 8) ? (acc2[2][r] + l2b[c0 + 32]) : -1e30f;
        float mx = fmaxf(fmaxf(v0, v1), v2);
        for (int msk = 1; msk < 16; msk <<= 1) mx = fmaxf(mx, __shfl_xor(mx, msk));
        float s = __expf(v0 - mx) + __expf(v1 - mx) + ((c0 < 8) ? __expf(v2 - mx) : 0.f);
        for (int msk = 1; msk < 16; msk <<= 1) s += __shfl_xor(s, msk);
        float lse = mx + __logf(s);
        int node = nbase + w * 16 + lg * 4 + r;
        if (node < N_NODES) {
            out[(size_t)node * 40 + c0] = v0 - lse;
            out[(size_t)node * 40 + c0 + 16] = v1 - lse;
            if (c0 < 8) out[(size_t)node * 40 + c0 + 32] = v2 - lse;
        }
    }
}

extern "C" void kernel_launch(void* const* d_in, const int* in_sizes, int n_in,
                              void* d_out, int out_size, void* d_ws, size_t ws_size,
                              hipStream_t stream) {
    const float* x  = (const float*)d_in[0];
    const int*   ei = (const int*)d_in[1];
    const float* gw1[3] = {(const float*)d_in[2],  (const float*)d_in[6],  (const float*)d_in[10]};
    const float* gb1[3] = {(const float*)d_in[3],  (const float*)d_in[7],  (const float*)d_in[11]};
    const float* gw2[3] = {(const float*)d_in[4],  (const float*)d_in[8],  (const float*)d_in[12]};
    const float* gb2[3] = {(const float*)d_in[5],  (const float*)d_in[9],  (const float*)d_in[13]};
    const float* l1w = (const float*)d_in[14];
    const float* l1b = (const float*)d_in[15];
    const float* l2w = (const float*)d_in[16];
    const float* l2b = (const float*)d_in[17];
    float* out = (float*)d_out;

    char* p = (char*)d_ws;
    auto alloc = [&](size_t bytes) { char* q = p; p += (bytes + 255) & ~(size_t)255; return q; };
    int* rp   = (int*)alloc(4 * (N_NODES + 1));
    int* cnt  = (int*)alloc(4 * N_NODES);
    int* bsum = (int*)alloc(4 * 256);
    int* colv = (int*)alloc(4 * (size_t)NEDGE);
    unsigned short* t  = (unsigned short*)alloc(2 * (size_t)N_NODES * 128);
    unsigned short* h1 = (unsigned short*)alloc(2 * (size_t)N_NODES * 128);
    unsigned short* h2 = (unsigned short*)alloc(2 * (size_t)N_NODES * 128);
    unsigned short* h3 = (unsigned short*)alloc(2 * (size_t)N_NODES * 128);
    unsigned short* xs = h3;   // alias: xs dead after layer-1 agg, h3 written in layer 3
    unsigned short* wt[6];
    for (int i = 0; i < 6; ++i) wt[i] = (unsigned short*)alloc(2 * 128 * 128);
    unsigned short* l1t = (unsigned short*)alloc(2 * 384 * 384);
    unsigned short* l2t = (unsigned short*)alloc(2 * 48 * 384);

    const int nb = (N_NODES + 1023) / 1024;     // 98
    // CSR build
    k_zero<<<(N_NODES + 255) / 256, 256, 0, stream>>>(cnt, N_NODES);
    k_count<<<(NEDGE + 255) / 256, 256, 0, stream>>>(ei, cnt);
    k_scan1<<<nb, 256, 0, stream>>>(cnt, rp, bsum);
    k_scan2<<<1, 256, 0, stream>>>(bsum, nb);
    k_scan3<<<nb, 256, 0, stream>>>(rp, bsum);
    k_zero<<<(N_NODES + 255) / 256, 256, 0, stream>>>(cnt, N_NODES);
    k_fill<<<(NEDGE + 255) / 256, 256, 0, stream>>>(ei, rp, cnt, colv);

    // weight prep (fragment-major bf16)
    for (int i = 0; i < 3; ++i) {
        k_wprep<<<(128 * 128 + 255) / 256, 256, 0, stream>>>(gw1[i], wt[2 * i], 128, 128, 128);
        k_wprep<<<(128 * 128 + 255) / 256, 256, 0, stream>>>(gw2[i], wt[2 * i + 1], 128, 128, 128);
    }
    k_wprep<<<(384 * 384 + 255) / 256, 256, 0, stream>>>(l1w, l1t, 384, 384, 384);
    k_wprep<<<(384 * 48 + 255) / 256, 256, 0, stream>>>(l2w, l2t, 384, 40, 48);

    // x -> sliced bf16
    k_xprep<<<8 * ((N_NODES * 8 + 255) / 256), 256, 0, stream>>>(x, xs);

    const int gagg = ((N_NODES + AGG_NODES - 1) / AGG_NODES) * 8;
    const int gtile = (N_NODES + 63) / 64;
    // layer 1
    k_aggs<<<gagg, 256, 0, stream>>>(xs, t, rp, colv);
    k_mlp<<<gtile, 256, 0, stream>>>(t, wt[0], gb1[0], wt[1], gb2[0], h1);
    // layer 2
    k_aggs<<<gagg, 256, 0, stream>>>(h1, t, rp, colv);
    k_mlp<<<gtile, 256, 0, stream>>>(t, wt[2], gb1[1], wt[3], gb2[1], h2);
    // layer 3
    k_aggs<<<gagg, 256, 0, stream>>>(h2, t, rp, colv);
    k_mlp<<<gtile, 256, 0, stream>>>(t, wt[4], gb1[2], wt[5], gb2[2], h3);
    // head
    k_final<<<gtile, 256, 0, stream>>>(h1, h2, h3, l1t, l1b, l2t, l2b, out);
}

// Round 5
// 548.522 us; speedup vs baseline: 1.7386x; 1.0823x over previous
//
#include <hip/hip_runtime.h>

#define N_NODES 100000
#define NEDGE   1600000
#define NHID    128
#define NCLASS  40

#define AGG_NODES 128
#define COLV_LDS  3072

using bf16x8 = __attribute__((ext_vector_type(8))) short;
using f32x4  = __attribute__((ext_vector_type(4))) float;

__device__ __forceinline__ float bf2f(unsigned short s) {
    unsigned u = ((unsigned)s) << 16; float f; __builtin_memcpy(&f, &u, 4); return f;
}
__device__ __forceinline__ unsigned short f2bf(float f) {
    unsigned u; __builtin_memcpy(&u, &f, 4);
    u = u + 0x7fffu + ((u >> 16) & 1u);          // RNE
    return (unsigned short)(u >> 16);
}

// global -> LDS direct (16B/lane). Dest: wave-uniform base + lane*16 (linear).
// Source: per-lane address (pre-swizzled to match swizzled LDS reader).
__device__ __forceinline__ void gld16(const void* g, void* l) {
    __builtin_amdgcn_global_load_lds(g, l, 16, 0, 0);
}

// ---------------- CSR build ----------------
__global__ void k_zero(int* __restrict__ p, int n) {
    int i = blockIdx.x * 256 + threadIdx.x;
    if (i < n) p[i] = 0;
}

__global__ void k_count(const int* __restrict__ ei, int* __restrict__ cnt) {
    int e = blockIdx.x * 256 + threadIdx.x;
    if (e < NEDGE) atomicAdd(&cnt[ei[NEDGE + e]], 1);   // dst row of edge_index
}

// block scans 1024 elements (256 thr x 4)
__global__ void k_scan1(const int* __restrict__ cnt, int* __restrict__ rp, int* __restrict__ bsum) {
    __shared__ int sh[256];
    int t = threadIdx.x, base = blockIdx.x * 1024;
    int v[4]; int s = 0;
    for (int k = 0; k < 4; ++k) { int i = base + t * 4 + k; v[k] = (i < N_NODES) ? cnt[i] : 0; s += v[k]; }
    sh[t] = s; __syncthreads();
    for (int off = 1; off < 256; off <<= 1) {
        int x = (t >= off) ? sh[t - off] : 0;
        __syncthreads();
        sh[t] += x;
        __syncthreads();
    }
    int excl = sh[t] - s;
    for (int k = 0; k < 4; ++k) { int i = base + t * 4 + k; if (i < N_NODES) rp[i] = excl; excl += v[k]; }
    if (t == 255) bsum[blockIdx.x] = sh[255];
}

__global__ void k_scan2(int* __restrict__ bsum, int nb) {
    __shared__ int sh[256];
    int t = threadIdx.x;
    int v = (t < nb) ? bsum[t] : 0;
    sh[t] = v; __syncthreads();
    for (int off = 1; off < 256; off <<= 1) {
        int x = (t >= off) ? sh[t - off] : 0;
        __syncthreads();
        sh[t] += x;
        __syncthreads();
    }
    if (t < nb) bsum[t] = sh[t] - v;   // exclusive block offsets
}

__global__ void k_scan3(int* __restrict__ rp, const int* __restrict__ bsum) {
    int base = blockIdx.x * 1024;
    int off = bsum[blockIdx.x];
    for (int k = 0; k < 4; ++k) {
        int i = base + threadIdx.x * 4 + k;
        if (i < N_NODES) rp[i] += off;
    }
    if (blockIdx.x == 0 && threadIdx.x == 0) rp[N_NODES] = NEDGE;
}

__global__ void k_fill(const int* __restrict__ ei, const int* __restrict__ rp,
                       int* __restrict__ cur, int* __restrict__ colv) {
    int e = blockIdx.x * 256 + threadIdx.x;
    if (e < NEDGE) {
        int d = ei[NEDGE + e];
        int p = atomicAdd(&cur[d], 1);
        colv[rp[d] + p] = ei[e];
    }
}

// ---------------- weight prep: fragment-major bf16 layout ----------------
// wt[((ot*KS + ks)*64 + lane)*8 + e] = w[k][c],  c = ot*16 + (lane&15),
// k = ks*32 + (lane>>4)*8 + e.  One B-fragment load = 64 lanes x contiguous 16B.
__global__ void k_wprep(const float* __restrict__ w, unsigned short* __restrict__ wt,
                        int K, int O, int Opad) {
    int idx = blockIdx.x * 256 + threadIdx.x;
    if (idx >= K * Opad) return;
    int kss = K >> 5;
    int e = idx & 7, lane = (idx >> 3) & 63, rest = idx >> 9;
    int ks = rest % kss, ot = rest / kss;
    int c = ot * 16 + (lane & 15);
    int k = ks * 32 + (lane >> 4) * 8 + e;
    float v = (c < O) ? w[k * O + c] : 0.f;
    wt[idx] = f2bf(v);
}

// ---------------- x -> sliced bf16 layout [8][N][16] ----------------
__global__ void k_xprep(const float* __restrict__ x, unsigned short* __restrict__ xs) {
    int s = blockIdx.x & 7;
    int rest = (blockIdx.x >> 3) * 256 + threadIdx.x;   // word index within slice, N*8 words
    if (rest >= N_NODES * 8) return;
    int n = rest >> 3, wrd = rest & 7;
    float2 v = *(const float2*)(x + (size_t)n * 128 + s * 16 + wrd * 2);
    ((unsigned*)xs)[(size_t)s * N_NODES * 8 + rest] =
        (unsigned)f2bf(v.x) | ((unsigned)f2bf(v.y) << 16);
}

// ---------------- aggregation, sliced + LDS colv + 8-deep gather MLP ----------------
__device__ __forceinline__ void acc8(float* acc, uint4 f, float m) {
    unsigned u[4] = {f.x, f.y, f.z, f.w};
    for (int d = 0; d < 4; ++d) {
        acc[2 * d]     = fmaf(m, bf2f((unsigned short)u[d]), acc[2 * d]);
        acc[2 * d + 1] = fmaf(m, bf2f((unsigned short)(u[d] >> 16)), acc[2 * d + 1]);
    }
}

__global__ __launch_bounds__(256) void k_aggs(const unsigned short* __restrict__ feat,
                                              unsigned short* __restrict__ tout,
                                              const int* __restrict__ rp,
                                              const int* __restrict__ colv) {
    __shared__ int scol[COLV_LDS];
    __shared__ int srp[AGG_NODES + 1];
    const int s = blockIdx.x & 7;
    const int chunk = blockIdx.x >> 3;
    const int tid = threadIdx.x;
    const int nbase = chunk * AGG_NODES;

    for (int i = tid; i <= AGG_NODES; i += 256) {
        int n = nbase + i;
        srp[i] = rp[n <= N_NODES ? n : N_NODES];
    }
    __syncthreads();
    const int ebase = srp[0];
    const int ecount = srp[AGG_NODES] - ebase;
    const int elds = ecount < COLV_LDS ? ecount : COLV_LDS;
    for (int i = tid; i < elds; i += 256) scol[i] = colv[ebase + i];
    __syncthreads();

    const unsigned* fs = (const unsigned*)feat + (size_t)s * N_NODES * 8;
    unsigned* ts = (unsigned*)tout + (size_t)s * N_NODES * 8;

    const int sub = tid >> 1, half = tid & 1;
    const int node = nbase + sub;
    if (node >= N_NODES) return;
    const int off = half * 4;
    const int e0 = srp[sub] - ebase, e1 = srp[sub + 1] - ebase;

    float acc[8];
    {
        uint4 a = *(const uint4*)(fs + (size_t)node * 8 + off);
        unsigned u[4] = {a.x, a.y, a.z, a.w};
        for (int d = 0; d < 4; ++d) {
            acc[2 * d]     = bf2f((unsigned short)u[d]);
            acc[2 * d + 1] = bf2f((unsigned short)(u[d] >> 16));
        }
    }

    for (int e = e0; e < e1; e += 8) {
        int j[8]; float m[8];
        #pragma unroll
        for (int k = 0; k < 8; ++k) {
            int ee = e + k;
            bool v = ee < e1;
            int idx = ee < COLV_LDS ? scol[ee] : colv[ebase + ee];
            j[k] = v ? idx : node;
            m[k] = v ? 1.f : 0.f;
        }
        uint4 f[8];
        #pragma unroll
        for (int k = 0; k < 8; ++k)
            f[k] = *(const uint4*)(fs + (size_t)j[k] * 8 + off);
        #pragma unroll
        for (int k = 0; k < 8; ++k) acc8(acc, f[k], m[k]);
    }

    uint4 o;
    o.x = (unsigned)f2bf(acc[0]) | ((unsigned)f2bf(acc[1]) << 16);
    o.y = (unsigned)f2bf(acc[2]) | ((unsigned)f2bf(acc[3]) << 16);
    o.z = (unsigned)f2bf(acc[4]) | ((unsigned)f2bf(acc[5]) << 16);
    o.w = (unsigned)f2bf(acc[6]) | ((unsigned)f2bf(acc[7]) << 16);
    *(uint4*)(ts + (size_t)node * 8 + off) = o;
}

// ---------------- fused GIN MLP: h = relu(relu(t@w1+b1)@w2+b2), 64-node tile ----------------
// tin / hout sliced [8][N][16] bf16; w1t/w2t fragment-major (KS=4, 8 ot-tiles).
// Staging via global_load_lds (linear dest, pre-swizzled per-lane source).
__global__ __launch_bounds__(256) void k_mlp(
    const unsigned short* __restrict__ tin,
    const unsigned short* __restrict__ w1t, const float* __restrict__ b1,
    const unsigned short* __restrict__ w2t, const float* __restrict__ b2,
    unsigned short* __restrict__ hout) {
    __shared__ __align__(16) char tlds[64 * 256];
    __shared__ __align__(16) char hlds[64 * 256];
    const int tid = threadIdx.x, lane = tid & 63, w = tid >> 6;
    const int l15 = lane & 15, lg = lane >> 4;
    const int nbase = blockIdx.x * 64;

    // stage t tile: 4 x 1KB wave-loads, direct to LDS
    #pragma unroll
    for (int i = 0; i < 4; ++i) {
        int byte = w * 4096 + i * 1024 + lane * 16;
        int r = byte >> 8, c8s = (byte >> 4) & 15;
        int c8 = c8s ^ (r & 7);
        int slice = c8 >> 1, half = c8 & 1;
        int node = nbase + r; if (node >= N_NODES) node = 0;
        gld16(tin + ((size_t)slice * N_NODES + node) * 16 + half * 8,
              tlds + w * 4096 + i * 1024);
    }

    // preload B1 fragments + bias (wave w owns out cols [32w, 32w+32))
    bf16x8 B1[2][4]; float bias1[2]; int cols[2];
    #pragma unroll
    for (int ot = 0; ot < 2; ++ot) {
        int c = (w * 2 + ot) * 16 + l15;
        cols[ot] = c; bias1[ot] = b1[c];
        #pragma unroll
        for (int ks = 0; ks < 4; ++ks)
            B1[ot][ks] = *(const bf16x8*)(w1t + ((size_t)((w * 2 + ot) * 4 + ks) * 64 + lane) * 8);
    }
    __syncthreads();   // vmcnt(0) drains staging

    // GEMM1 -> relu -> hlds (A double-buffered over m)
    {
        bf16x8 A[2][4];
        #pragma unroll
        for (int ks = 0; ks < 4; ++ks)
            A[0][ks] = *(const bf16x8*)(tlds + l15 * 256 + ((ks * 64 + lg * 16) ^ ((l15 & 7) << 4)));
        #pragma unroll
        for (int m = 0; m < 4; ++m) {
            int cur = m & 1, nxt = cur ^ 1;
            if (m < 3) {
                int row = (m + 1) * 16 + l15;
                #pragma unroll
                for (int ks = 0; ks < 4; ++ks)
                    A[nxt][ks] = *(const bf16x8*)(tlds + row * 256 + ((ks * 64 + lg * 16) ^ ((row & 7) << 4)));
            }
            #pragma unroll
            for (int ot = 0; ot < 2; ++ot) {
                f32x4 acc = {0.f, 0.f, 0.f, 0.f};
                #pragma unroll
                for (int ks = 0; ks < 4; ++ks)
                    acc = __builtin_amdgcn_mfma_f32_16x16x32_bf16(A[cur][ks], B1[ot][ks], acc, 0, 0, 0);
                int c2 = cols[ot] * 2;
                #pragma unroll
                for (int r = 0; r < 4; ++r) {
                    int row = m * 16 + lg * 4 + r;
                    float v = acc[r] + bias1[ot]; v = v > 0.f ? v : 0.f;
                    *(unsigned short*)(hlds + row * 256 + (c2 ^ ((row & 7) << 4))) = f2bf(v);
                }
            }
        }
    }

    // preload B2
    bf16x8 B2[2][4]; float bias2[2];
    #pragma unroll
    for (int ot = 0; ot < 2; ++ot) {
        bias2[ot] = b2[cols[ot]];
        #pragma unroll
        for (int ks = 0; ks < 4; ++ks)
            B2[ot][ks] = *(const bf16x8*)(w2t + ((size_t)((w * 2 + ot) * 4 + ks) * 64 + lane) * 8);
    }
    __syncthreads();

    // GEMM2 -> relu -> global (sliced layout), A double-buffered over m
    {
        bf16x8 A[2][4];
        #pragma unroll
        for (int ks = 0; ks < 4; ++ks)
            A[0][ks] = *(const bf16x8*)(hlds + l15 * 256 + ((ks * 64 + lg * 16) ^ ((l15 & 7) << 4)));
        #pragma unroll
        for (int m = 0; m < 4; ++m) {
            int cur = m & 1, nxt = cur ^ 1;
            if (m < 3) {
                int row = (m + 1) * 16 + l15;
                #pragma unroll
                for (int ks = 0; ks < 4; ++ks)
                    A[nxt][ks] = *(const bf16x8*)(hlds + row * 256 + ((ks * 64 + lg * 16) ^ ((row & 7) << 4)));
            }
            #pragma unroll
            for (int ot = 0; ot < 2; ++ot) {
                f32x4 acc = {0.f, 0.f, 0.f, 0.f};
                #pragma unroll
                for (int ks = 0; ks < 4; ++ks)
                    acc = __builtin_amdgcn_mfma_f32_16x16x32_bf16(A[cur][ks], B2[ot][ks], acc, 0, 0, 0);
                int cslice = cols[ot] >> 4, cw = cols[ot] & 15;
                #pragma unroll
                for (int r = 0; r < 4; ++r) {
                    int node = nbase + m * 16 + lg * 4 + r;
                    if (node < N_NODES) {
                        float v = acc[r] + bias2[ot]; v = v > 0.f ? v : 0.f;
                        hout[((size_t)cslice * N_NODES + node) * 16 + cw] = f2bf(v);
                    }
                }
            }
        }
    }
}

// ---------------- fused head: relu(concat@lin1+b) @ lin2 + b -> log_softmax ----------------
// l1t fragment-major (KS=12, 24 ot); l2t fragment-major (KS=12, 3 ot, cols padded to 48).
// Staging via global_load_lds; B and A double-buffered in both GEMMs.
__global__ __launch_bounds__(256) void k_final(
    const unsigned short* __restrict__ h1, const unsigned short* __restrict__ h2,
    const unsigned short* __restrict__ h3,
    const unsigned short* __restrict__ l1t, const float* __restrict__ l1b,
    const unsigned short* __restrict__ l2t, const float* __restrict__ l2b,
    float* __restrict__ out) {
    __shared__ __align__(16) char lds[64 * 768];   // 48KB: A-tile then hidden
    const int tid = threadIdx.x, lane = tid & 63, w = tid >> 6;
    const int l15 = lane & 15, lg = lane >> 4;
    const int nbase = blockIdx.x * 64;

    // stage concat(h1,h2,h3) tile: 12 x 1KB wave-loads direct to LDS
    #pragma unroll
    for (int i = 0; i < 12; ++i) {
        unsigned byte = (unsigned)(w * 12288 + i * 1024 + lane * 16);
        unsigned r = byte / 768u;
        unsigned rem = byte - r * 768u;
        int c8 = (int)(rem >> 4) ^ (int)(r & 7);
        int part = c8 >> 4, c8p = c8 & 15;
        int slice = c8p >> 1, half = c8p & 1;
        int node = nbase + (int)r; if (node >= N_NODES) node = 0;
        const unsigned short* hp = part == 0 ? h1 : (part == 1 ? h2 : h3);
        gld16(hp + ((size_t)slice * N_NODES + node) * 16 + half * 8,
              lds + w * 12288 + i * 1024);
    }

    // preload lin1 B for ks=0 (global, independent of staging)
    bf16x8 B[2][6];
    #pragma unroll
    for (int ot = 0; ot < 6; ++ot)
        B[0][ot] = *(const bf16x8*)(l1t + ((size_t)((w * 6 + ot) * 12) * 64 + lane) * 8);
    __syncthreads();   // vmcnt(0) drains staging

    // lin1: wave w owns out cols [96w, 96w+96); B+A double-buffered over ks
    f32x4 acc[4][6];
    #pragma unroll
    for (int m = 0; m < 4; ++m)
        #pragma unroll
        for (int ot = 0; ot < 6; ++ot) acc[m][ot] = {0.f, 0.f, 0.f, 0.f};
    {
        bf16x8 A[2][4];
        #pragma unroll
        for (int m = 0; m < 4; ++m) {
            int row = m * 16 + l15;
            A[0][m] = *(const bf16x8*)(lds + row * 768 + ((lg * 16) ^ ((row & 7) << 4)));
        }
        #pragma unroll
        for (int ks = 0; ks < 12; ++ks) {
            int cur = ks & 1, nxt = cur ^ 1;
            if (ks < 11) {
                #pragma unroll
                for (int ot = 0; ot < 6; ++ot)
                    B[nxt][ot] = *(const bf16x8*)(l1t + ((size_t)((w * 6 + ot) * 12 + ks + 1) * 64 + lane) * 8);
                #pragma unroll
                for (int m = 0; m < 4; ++m) {
                    int row = m * 16 + l15;
                    A[nxt][m] = *(const bf16x8*)(lds + row * 768 + (((ks + 1) * 64 + lg * 16) ^ ((row & 7) << 4)));
                }
            }
            #pragma unroll
            for (int ot = 0; ot < 6; ++ot)
                #pragma unroll
                for (int m = 0; m < 4; ++m)
                    acc[m][ot] = __builtin_amdgcn_mfma_f32_16x16x32_bf16(A[cur][m], B[cur][ot], acc[m][ot], 0, 0, 0);
        }
    }
    __syncthreads();   // everyone done reading A-tile

    // relu + write hidden (bf16) into same LDS
    #pragma unroll
    for (int ot = 0; ot < 6; ++ot) {
        int c = (w * 6 + ot) * 16 + l15;
        float bias = l1b[c];
        #pragma unroll
        for (int m = 0; m < 4; ++m)
            #pragma unroll
            for (int r = 0; r < 4; ++r) {
                int row = m * 16 + lg * 4 + r;
                float v = acc[m][ot][r] + bias; v = v > 0.f ? v : 0.f;
                *(unsigned short*)(lds + row * 768 + ((c * 2) ^ ((row & 7) << 4))) = f2bf(v);
            }
    }
    __syncthreads();

    // lin2: wave w owns rows [16w, 16w+16); B+A double-buffered over ks
    f32x4 acc2[3];
    #pragma unroll
    for (int ot = 0; ot < 3; ++ot) acc2[ot] = {0.f, 0.f, 0.f, 0.f};
    {
        const int row = w * 16 + l15;
        bf16x8 C2[2][3]; bf16x8 A2[2];
        #pragma unroll
        for (int ot = 0; ot < 3; ++ot)
            C2[0][ot] = *(const bf16x8*)(l2t + ((size_t)(ot * 12) * 64 + lane) * 8);
        A2[0] = *(const bf16x8*)(lds + row * 768 + ((lg * 16) ^ ((row & 7) << 4)));
        #pragma unroll
        for (int ks = 0; ks < 12; ++ks) {
            int cur = ks & 1, nxt = cur ^ 1;
            if (ks < 11) {
                #pragma unroll
                for (int ot = 0; ot < 3; ++ot)
                    C2[nxt][ot] = *(const bf16x8*)(l2t + ((size_t)(ot * 12 + ks + 1) * 64 + lane) * 8);
                A2[nxt] = *(const bf16x8*)(lds + row * 768 + (((ks + 1) * 64 + lg * 16) ^ ((row & 7) << 4)));
            }
            #pragma unroll
            for (int ot = 0; ot < 3; ++ot)
                acc2[ot] = __builtin_amdgcn_mfma_f32_16x16x32_bf16(A2[cur], C2[cur][ot], acc2[ot], 0, 0, 0);
        }
    }

    // bias + log_softmax over 40 classes (row spread over 16 lanes x 3 regs)
    int c0 = l15;
    #pragma unroll
    for (int r = 0; r < 4; ++r) {
        float v0 = acc2[0][r] + l2b[c0];
        float v1 = acc2[1][r] + l2b[c0 + 16];
        float v2 = (c0 < 8) ? (acc2[2][r] + l2b[c0 + 32]) : -1e30f;
        float mx = fmaxf(fmaxf(v0, v1), v2);
        for (int msk = 1; msk < 16; msk <<= 1) mx = fmaxf(mx, __shfl_xor(mx, msk));
        float s = __expf(v0 - mx) + __expf(v1 - mx) + ((c0 < 8) ? __expf(v2 - mx) : 0.f);
        for (int msk = 1; msk < 16; msk <<= 1) s += __shfl_xor(s, msk);
        float lse = mx + __logf(s);
        int node = nbase + w * 16 + lg * 4 + r;
        if (node < N_NODES) {
            out[(size_t)node * 40 + c0] = v0 - lse;
            out[(size_t)node * 40 + c0 + 16] = v1 - lse;
            if (c0 < 8) out[(size_t)node * 40 + c0 + 32] = v2 - lse;
        }
    }
}

extern "C" void kernel_launch(void* const* d_in, const int* in_sizes, int n_in,
                              void* d_out, int out_size, void* d_ws, size_t ws_size,
                              hipStream_t stream) {
    const float* x  = (const float*)d_in[0];
    const int*   ei = (const int*)d_in[1];
    const float* gw1[3] = {(const float*)d_in[2],  (const float*)d_in[6],  (const float*)d_in[10]};
    const float* gb1[3] = {(const float*)d_in[3],  (const float*)d_in[7],  (const float*)d_in[11]};
    const float* gw2[3] = {(const float*)d_in[4],  (const float*)d_in[8],  (const float*)d_in[12]};
    const float* gb2[3] = {(const float*)d_in[5],  (const float*)d_in[9],  (const float*)d_in[13]};
    const float* l1w = (const float*)d_in[14];
    const float* l1b = (const float*)d_in[15];
    const float* l2w = (const float*)d_in[16];
    const float* l2b = (const float*)d_in[17];
    float* out = (float*)d_out;

    char* p = (char*)d_ws;
    auto alloc = [&](size_t bytes) { char* q = p; p += (bytes + 255) & ~(size_t)255; return q; };
    int* rp   = (int*)alloc(4 * (N_NODES + 1));
    int* cnt  = (int*)alloc(4 * N_NODES);
    int* bsum = (int*)alloc(4 * 256);
    int* colv = (int*)alloc(4 * (size_t)NEDGE);
    unsigned short* t  = (unsigned short*)alloc(2 * (size_t)N_NODES * 128);
    unsigned short* h1 = (unsigned short*)alloc(2 * (size_t)N_NODES * 128);
    unsigned short* h2 = (unsigned short*)alloc(2 * (size_t)N_NODES * 128);
    unsigned short* h3 = (unsigned short*)alloc(2 * (size_t)N_NODES * 128);
    unsigned short* xs = h3;   // alias: xs dead after layer-1 agg, h3 written in layer 3
    unsigned short* wt[6];
    for (int i = 0; i < 6; ++i) wt[i] = (unsigned short*)alloc(2 * 128 * 128);
    unsigned short* l1t = (unsigned short*)alloc(2 * 384 * 384);
    unsigned short* l2t = (unsigned short*)alloc(2 * 48 * 384);

    const int nb = (N_NODES + 1023) / 1024;     // 98
    // CSR build
    k_zero<<<(N_NODES + 255) / 256, 256, 0, stream>>>(cnt, N_NODES);
    k_count<<<(NEDGE + 255) / 256, 256, 0, stream>>>(ei, cnt);
    k_scan1<<<nb, 256, 0, stream>>>(cnt, rp, bsum);
    k_scan2<<<1, 256, 0, stream>>>(bsum, nb);
    k_scan3<<<nb, 256, 0, stream>>>(rp, bsum);
    k_zero<<<(N_NODES + 255) / 256, 256, 0, stream>>>(cnt, N_NODES);
    k_fill<<<(NEDGE + 255) / 256, 256, 0, stream>>>(ei, rp, cnt, colv);

    // weight prep (fragment-major bf16)
    for (int i = 0; i < 3; ++i) {
        k_wprep<<<(128 * 128 + 255) / 256, 256, 0, stream>>>(gw1[i], wt[2 * i], 128, 128, 128);
        k_wprep<<<(128 * 128 + 255) / 256, 256, 0, stream>>>(gw2[i], wt[2 * i + 1], 128, 128, 128);
    }
    k_wprep<<<(384 * 384 + 255) / 256, 256, 0, stream>>>(l1w, l1t, 384, 384, 384);
    k_wprep<<<(384 * 48 + 255) / 256, 256, 0, stream>>>(l2w, l2t, 384, 40, 48);

    // x -> sliced bf16
    k_xprep<<<8 * ((N_NODES * 8 + 255) / 256), 256, 0, stream>>>(x, xs);

    const int gagg = ((N_NODES + AGG_NODES - 1) / AGG_NODES) * 8;
    const int gtile = (N_NODES + 63) / 64;
    // layer 1
    k_aggs<<<gagg, 256, 0, stream>>>(xs, t, rp, colv);
    k_mlp<<<gtile, 256, 0, stream>>>(t, wt[0], gb1[0], wt[1], gb2[0], h1);
    // layer 2
    k_aggs<<<gagg, 256, 0, stream>>>(h1, t, rp, colv);
    k_mlp<<<gtile, 256, 0, stream>>>(t, wt[2], gb1[1], wt[3], gb2[1], h2);
    // layer 3
    k_aggs<<<gagg, 256, 0, stream>>>(h2, t, rp, colv);
    k_mlp<<<gtile, 256, 0, stream>>>(t, wt[4], gb1[2], wt[5], gb2[2], h3);
    // head
    k_final<<<gtile, 256, 0, stream>>>(h1, h2, h3, l1t, l1b, l2t, l2b, out);
}

// Round 6
// 522.378 us; speedup vs baseline: 1.8257x; 1.0500x over previous
//
#include <hip/hip_runtime.h>

#define N_NODES 100000
#define NEDGE   1600000
#define NHID    128
#define NCLASS  40

#define AGG_NODES 128
#define COLV_LDS  3072
#define FILL_SLICES 8
#define FILL_RANGE  12500   // N_NODES / FILL_SLICES

using bf16x8 = __attribute__((ext_vector_type(8))) short;
using f32x4  = __attribute__((ext_vector_type(4))) float;

__device__ __forceinline__ float bf2f(unsigned short s) {
    unsigned u = ((unsigned)s) << 16; float f; __builtin_memcpy(&f, &u, 4); return f;
}
__device__ __forceinline__ unsigned short f2bf(float f) {
    unsigned u; __builtin_memcpy(&u, &f, 4);
    u = u + 0x7fffu + ((u >> 16) & 1u);          // RNE
    return (unsigned short)(u >> 16);
}

// global -> LDS direct (16B/lane). Dest: wave-uniform base + lane*16 (linear).
// Source: per-lane address (pre-swizzled to match swizzled LDS reader).
__device__ __forceinline__ void gld16(const void* g, void* l) {
    __builtin_amdgcn_global_load_lds(g, l, 16, 0, 0);
}

// ---------------- CSR build ----------------
__global__ void k_zero(int* __restrict__ p, int n) {
    int i = blockIdx.x * 256 + threadIdx.x;
    if (i < n) p[i] = 0;
}

__global__ void k_count(const int* __restrict__ ei, int* __restrict__ cnt) {
    int e = blockIdx.x * 256 + threadIdx.x;
    if (e < NEDGE) atomicAdd(&cnt[ei[NEDGE + e]], 1);   // dst row of edge_index
}

// block scans 1024 elements (256 thr x 4)
__global__ void k_scan1(const int* __restrict__ cnt, int* __restrict__ rp, int* __restrict__ bsum) {
    __shared__ int sh[256];
    int t = threadIdx.x, base = blockIdx.x * 1024;
    int v[4]; int s = 0;
    for (int k = 0; k < 4; ++k) { int i = base + t * 4 + k; v[k] = (i < N_NODES) ? cnt[i] : 0; s += v[k]; }
    sh[t] = s; __syncthreads();
    for (int off = 1; off < 256; off <<= 1) {
        int x = (t >= off) ? sh[t - off] : 0;
        __syncthreads();
        sh[t] += x;
        __syncthreads();
    }
    int excl = sh[t] - s;
    for (int k = 0; k < 4; ++k) { int i = base + t * 4 + k; if (i < N_NODES) rp[i] = excl; excl += v[k]; }
    if (t == 255) bsum[blockIdx.x] = sh[255];
}

__global__ void k_scan2(int* __restrict__ bsum, int nb) {
    __shared__ int sh[256];
    int t = threadIdx.x;
    int v = (t < nb) ? bsum[t] : 0;
    sh[t] = v; __syncthreads();
    for (int off = 1; off < 256; off <<= 1) {
        int x = (t >= off) ? sh[t - off] : 0;
        __syncthreads();
        sh[t] += x;
        __syncthreads();
    }
    if (t < nb) bsum[t] = sh[t] - v;   // exclusive block offsets
}

__global__ void k_scan3(int* __restrict__ rp, const int* __restrict__ bsum) {
    int base = blockIdx.x * 1024;
    int off = bsum[blockIdx.x];
    for (int k = 0; k < 4; ++k) {
        int i = base + threadIdx.x * 4 + k;
        if (i < N_NODES) rp[i] += off;
    }
    if (blockIdx.x == 0 && threadIdx.x == 0) rp[N_NODES] = NEDGE;
}

// range-partitioned fill: slice = blockIdx&7 owns dst in [slice*12500,(slice+1)*12500).
// Each slice's colv segment ~800KB stays resident in its (round-robin pinned) XCD L2
// -> full-line writebacks, no cross-XCD line ping-pong.
__global__ __launch_bounds__(256) void k_fillr(const int* __restrict__ ei, const int* __restrict__ rp,
                                               int* __restrict__ cur, int* __restrict__ colv) {
    int slice = blockIdx.x & 7;
    int e = (blockIdx.x >> 3) * 256 + threadIdx.x;
    if (e >= NEDGE) return;
    int d = ei[NEDGE + e];
    int lo = slice * FILL_RANGE;
    if (d >= lo && d < lo + FILL_RANGE) {
        int p = atomicAdd(&cur[d], 1);
        colv[rp[d] + p] = ei[e];
    }
}

// ---------------- weight prep: fragment-major bf16 layout ----------------
// wt[((ot*KS + ks)*64 + lane)*8 + e] = w[k][c],  c = ot*16 + (lane&15),
// k = ks*32 + (lane>>4)*8 + e.  One B-fragment load = 64 lanes x contiguous 16B.
__global__ void k_wprep(const float* __restrict__ w, unsigned short* __restrict__ wt,
                        int K, int O, int Opad) {
    int idx = blockIdx.x * 256 + threadIdx.x;
    if (idx >= K * Opad) return;
    int kss = K >> 5;
    int e = idx & 7, lane = (idx >> 3) & 63, rest = idx >> 9;
    int ks = rest % kss, ot = rest / kss;
    int c = ot * 16 + (lane & 15);
    int k = ks * 32 + (lane >> 4) * 8 + e;
    float v = (c < O) ? w[k * O + c] : 0.f;
    wt[idx] = f2bf(v);
}

// ---------------- x -> sliced bf16 layout [8][N][16] ----------------
__global__ void k_xprep(const float* __restrict__ x, unsigned short* __restrict__ xs) {
    int s = blockIdx.x & 7;
    int rest = (blockIdx.x >> 3) * 256 + threadIdx.x;   // word index within slice, N*8 words
    if (rest >= N_NODES * 8) return;
    int n = rest >> 3, wrd = rest & 7;
    float2 v = *(const float2*)(x + (size_t)n * 128 + s * 16 + wrd * 2);
    ((unsigned*)xs)[(size_t)s * N_NODES * 8 + rest] =
        (unsigned)f2bf(v.x) | ((unsigned)f2bf(v.y) << 16);
}

// ---------------- aggregation, sliced + LDS colv + 8-deep gather MLP ----------------
__device__ __forceinline__ void acc8(float* acc, uint4 f, float m) {
    unsigned u[4] = {f.x, f.y, f.z, f.w};
    for (int d = 0; d < 4; ++d) {
        acc[2 * d]     = fmaf(m, bf2f((unsigned short)u[d]), acc[2 * d]);
        acc[2 * d + 1] = fmaf(m, bf2f((unsigned short)(u[d] >> 16)), acc[2 * d + 1]);
    }
}

__global__ __launch_bounds__(256) void k_aggs(const unsigned short* __restrict__ feat,
                                              unsigned short* __restrict__ tout,
                                              const int* __restrict__ rp,
                                              const int* __restrict__ colv) {
    __shared__ int scol[COLV_LDS];
    __shared__ int srp[AGG_NODES + 1];
    const int s = blockIdx.x & 7;
    const int chunk = blockIdx.x >> 3;
    const int tid = threadIdx.x;
    const int nbase = chunk * AGG_NODES;

    for (int i = tid; i <= AGG_NODES; i += 256) {
        int n = nbase + i;
        srp[i] = rp[n <= N_NODES ? n : N_NODES];
    }
    __syncthreads();
    const int ebase = srp[0];
    const int ecount = srp[AGG_NODES] - ebase;
    const int elds = ecount < COLV_LDS ? ecount : COLV_LDS;
    for (int i = tid; i < elds; i += 256) scol[i] = colv[ebase + i];
    __syncthreads();

    const unsigned* fs = (const unsigned*)feat + (size_t)s * N_NODES * 8;
    unsigned* ts = (unsigned*)tout + (size_t)s * N_NODES * 8;

    const int sub = tid >> 1, half = tid & 1;
    const int node = nbase + sub;
    if (node >= N_NODES) return;
    const int off = half * 4;
    const int e0 = srp[sub] - ebase, e1 = srp[sub + 1] - ebase;

    float acc[8];
    {
        uint4 a = *(const uint4*)(fs + (size_t)node * 8 + off);
        unsigned u[4] = {a.x, a.y, a.z, a.w};
        for (int d = 0; d < 4; ++d) {
            acc[2 * d]     = bf2f((unsigned short)u[d]);
            acc[2 * d + 1] = bf2f((unsigned short)(u[d] >> 16));
        }
    }

    for (int e = e0; e < e1; e += 8) {
        int j[8]; float m[8];
        #pragma unroll
        for (int k = 0; k < 8; ++k) {
            int ee = e + k;
            bool v = ee < e1;
            int idx = ee < COLV_LDS ? scol[ee] : colv[ebase + ee];
            j[k] = v ? idx : node;
            m[k] = v ? 1.f : 0.f;
        }
        uint4 f[8];
        #pragma unroll
        for (int k = 0; k < 8; ++k)
            f[k] = *(const uint4*)(fs + (size_t)j[k] * 8 + off);
        #pragma unroll
        for (int k = 0; k < 8; ++k) acc8(acc, f[k], m[k]);
    }

    uint4 o;
    o.x = (unsigned)f2bf(acc[0]) | ((unsigned)f2bf(acc[1]) << 16);
    o.y = (unsigned)f2bf(acc[2]) | ((unsigned)f2bf(acc[3]) << 16);
    o.z = (unsigned)f2bf(acc[4]) | ((unsigned)f2bf(acc[5]) << 16);
    o.w = (unsigned)f2bf(acc[6]) | ((unsigned)f2bf(acc[7]) << 16);
    *(uint4*)(ts + (size_t)node * 8 + off) = o;
}

// ---------------- fused GIN MLP: h = relu(relu(t@w1+b1)@w2+b2), 64-node tile ----------------
// tin / hout sliced [8][N][16] bf16; w1t/w2t fragment-major (KS=4, 8 ot-tiles).
// Staging via global_load_lds (linear dest, pre-swizzled per-lane source).
__global__ __launch_bounds__(256) void k_mlp(
    const unsigned short* __restrict__ tin,
    const unsigned short* __restrict__ w1t, const float* __restrict__ b1,
    const unsigned short* __restrict__ w2t, const float* __restrict__ b2,
    unsigned short* __restrict__ hout) {
    __shared__ __align__(16) char tlds[64 * 256];
    __shared__ __align__(16) char hlds[64 * 256];
    const int tid = threadIdx.x, lane = tid & 63, w = tid >> 6;
    const int l15 = lane & 15, lg = lane >> 4;
    const int nbase = blockIdx.x * 64;

    // stage t tile: 4 x 1KB wave-loads, direct to LDS
    #pragma unroll
    for (int i = 0; i < 4; ++i) {
        int byte = w * 4096 + i * 1024 + lane * 16;
        int r = byte >> 8, c8s = (byte >> 4) & 15;
        int c8 = c8s ^ (r & 7);
        int slice = c8 >> 1, half = c8 & 1;
        int node = nbase + r; if (node >= N_NODES) node = 0;
        gld16(tin + ((size_t)slice * N_NODES + node) * 16 + half * 8,
              tlds + w * 4096 + i * 1024);
    }

    // preload B1 fragments + bias (wave w owns out cols [32w, 32w+32))
    bf16x8 B1[2][4]; float bias1[2]; int cols[2];
    #pragma unroll
    for (int ot = 0; ot < 2; ++ot) {
        int c = (w * 2 + ot) * 16 + l15;
        cols[ot] = c; bias1[ot] = b1[c];
        #pragma unroll
        for (int ks = 0; ks < 4; ++ks)
            B1[ot][ks] = *(const bf16x8*)(w1t + ((size_t)((w * 2 + ot) * 4 + ks) * 64 + lane) * 8);
    }
    __syncthreads();   // vmcnt(0) drains staging

    // GEMM1 -> relu -> hlds (A double-buffered over m)
    {
        bf16x8 A[2][4];
        #pragma unroll
        for (int ks = 0; ks < 4; ++ks)
            A[0][ks] = *(const bf16x8*)(tlds + l15 * 256 + ((ks * 64 + lg * 16) ^ ((l15 & 7) << 4)));
        #pragma unroll
        for (int m = 0; m < 4; ++m) {
            int cur = m & 1, nxt = cur ^ 1;
            if (m < 3) {
                int row = (m + 1) * 16 + l15;
                #pragma unroll
                for (int ks = 0; ks < 4; ++ks)
                    A[nxt][ks] = *(const bf16x8*)(tlds + row * 256 + ((ks * 64 + lg * 16) ^ ((row & 7) << 4)));
            }
            #pragma unroll
            for (int ot = 0; ot < 2; ++ot) {
                f32x4 acc = {0.f, 0.f, 0.f, 0.f};
                #pragma unroll
                for (int ks = 0; ks < 4; ++ks)
                    acc = __builtin_amdgcn_mfma_f32_16x16x32_bf16(A[cur][ks], B1[ot][ks], acc, 0, 0, 0);
                int c2 = cols[ot] * 2;
                #pragma unroll
                for (int r = 0; r < 4; ++r) {
                    int row = m * 16 + lg * 4 + r;
                    float v = acc[r] + bias1[ot]; v = v > 0.f ? v : 0.f;
                    *(unsigned short*)(hlds + row * 256 + (c2 ^ ((row & 7) << 4))) = f2bf(v);
                }
            }
        }
    }

    // preload B2
    bf16x8 B2[2][4]; float bias2[2];
    #pragma unroll
    for (int ot = 0; ot < 2; ++ot) {
        bias2[ot] = b2[cols[ot]];
        #pragma unroll
        for (int ks = 0; ks < 4; ++ks)
            B2[ot][ks] = *(const bf16x8*)(w2t + ((size_t)((w * 2 + ot) * 4 + ks) * 64 + lane) * 8);
    }
    __syncthreads();

    // GEMM2 -> relu -> global (sliced layout), A double-buffered over m
    {
        bf16x8 A[2][4];
        #pragma unroll
        for (int ks = 0; ks < 4; ++ks)
            A[0][ks] = *(const bf16x8*)(hlds + l15 * 256 + ((ks * 64 + lg * 16) ^ ((l15 & 7) << 4)));
        #pragma unroll
        for (int m = 0; m < 4; ++m) {
            int cur = m & 1, nxt = cur ^ 1;
            if (m < 3) {
                int row = (m + 1) * 16 + l15;
                #pragma unroll
                for (int ks = 0; ks < 4; ++ks)
                    A[nxt][ks] = *(const bf16x8*)(hlds + row * 256 + ((ks * 64 + lg * 16) ^ ((row & 7) << 4)));
            }
            #pragma unroll
            for (int ot = 0; ot < 2; ++ot) {
                f32x4 acc = {0.f, 0.f, 0.f, 0.f};
                #pragma unroll
                for (int ks = 0; ks < 4; ++ks)
                    acc = __builtin_amdgcn_mfma_f32_16x16x32_bf16(A[cur][ks], B2[ot][ks], acc, 0, 0, 0);
                int cslice = cols[ot] >> 4, cw = cols[ot] & 15;
                #pragma unroll
                for (int r = 0; r < 4; ++r) {
                    int node = nbase + m * 16 + lg * 4 + r;
                    if (node < N_NODES) {
                        float v = acc[r] + bias2[ot]; v = v > 0.f ? v : 0.f;
                        hout[((size_t)cslice * N_NODES + node) * 16 + cw] = f2bf(v);
                    }
                }
            }
        }
    }
}

// ---------------- fused head: relu(concat@lin1+b) @ lin2 + b -> log_softmax ----------------
// l1t fragment-major (KS=12, 24 ot); l2t fragment-major (KS=12, 3 ot, cols padded to 48).
// Staging via global_load_lds; B and A double-buffered in both GEMMs.
__global__ __launch_bounds__(256) void k_final(
    const unsigned short* __restrict__ h1, const unsigned short* __restrict__ h2,
    const unsigned short* __restrict__ h3,
    const unsigned short* __restrict__ l1t, const float* __restrict__ l1b,
    const unsigned short* __restrict__ l2t, const float* __restrict__ l2b,
    float* __restrict__ out) {
    __shared__ __align__(16) char lds[64 * 768];   // 48KB: A-tile then hidden
    const int tid = threadIdx.x, lane = tid & 63, w = tid >> 6;
    const int l15 = lane & 15, lg = lane >> 4;
    const int nbase = blockIdx.x * 64;

    // stage concat(h1,h2,h3) tile: 12 x 1KB wave-loads direct to LDS
    #pragma unroll
    for (int i = 0; i < 12; ++i) {
        unsigned byte = (unsigned)(w * 12288 + i * 1024 + lane * 16);
        unsigned r = byte / 768u;
        unsigned rem = byte - r * 768u;
        int c8 = (int)(rem >> 4) ^ (int)(r & 7);
        int part = c8 >> 4, c8p = c8 & 15;
        int slice = c8p >> 1, half = c8p & 1;
        int node = nbase + (int)r; if (node >= N_NODES) node = 0;
        const unsigned short* hp = part == 0 ? h1 : (part == 1 ? h2 : h3);
        gld16(hp + ((size_t)slice * N_NODES + node) * 16 + half * 8,
              lds + w * 12288 + i * 1024);
    }

    // preload lin1 B for ks=0 (global, independent of staging)
    bf16x8 B[2][6];
    #pragma unroll
    for (int ot = 0; ot < 6; ++ot)
        B[0][ot] = *(const bf16x8*)(l1t + ((size_t)((w * 6 + ot) * 12) * 64 + lane) * 8);
    __syncthreads();   // vmcnt(0) drains staging

    // lin1: wave w owns out cols [96w, 96w+96); B+A double-buffered over ks
    f32x4 acc[4][6];
    #pragma unroll
    for (int m = 0; m < 4; ++m)
        #pragma unroll
        for (int ot = 0; ot < 6; ++ot) acc[m][ot] = {0.f, 0.f, 0.f, 0.f};
    {
        bf16x8 A[2][4];
        #pragma unroll
        for (int m = 0; m < 4; ++m) {
            int row = m * 16 + l15;
            A[0][m] = *(const bf16x8*)(lds + row * 768 + ((lg * 16) ^ ((row & 7) << 4)));
        }
        #pragma unroll
        for (int ks = 0; ks < 12; ++ks) {
            int cur = ks & 1, nxt = cur ^ 1;
            if (ks < 11) {
                #pragma unroll
                for (int ot = 0; ot < 6; ++ot)
                    B[nxt][ot] = *(const bf16x8*)(l1t + ((size_t)((w * 6 + ot) * 12 + ks + 1) * 64 + lane) * 8);
                #pragma unroll
                for (int m = 0; m < 4; ++m) {
                    int row = m * 16 + l15;
                    A[nxt][m] = *(const bf16x8*)(lds + row * 768 + (((ks + 1) * 64 + lg * 16) ^ ((row & 7) << 4)));
                }
            }
            #pragma unroll
            for (int ot = 0; ot < 6; ++ot)
                #pragma unroll
                for (int m = 0; m < 4; ++m)
                    acc[m][ot] = __builtin_amdgcn_mfma_f32_16x16x32_bf16(A[cur][m], B[cur][ot], acc[m][ot], 0, 0, 0);
        }
    }
    __syncthreads();   // everyone done reading A-tile

    // relu + write hidden (bf16) into same LDS
    #pragma unroll
    for (int ot = 0; ot < 6; ++ot) {
        int c = (w * 6 + ot) * 16 + l15;
        float bias = l1b[c];
        #pragma unroll
        for (int m = 0; m < 4; ++m)
            #pragma unroll
            for (int r = 0; r < 4; ++r) {
                int row = m * 16 + lg * 4 + r;
                float v = acc[m][ot][r] + bias; v = v > 0.f ? v : 0.f;
                *(unsigned short*)(lds + row * 768 + ((c * 2) ^ ((row & 7) << 4))) = f2bf(v);
            }
    }
    __syncthreads();

    // lin2: wave w owns rows [16w, 16w+16); B+A double-buffered over ks
    f32x4 acc2[3];
    #pragma unroll
    for (int ot = 0; ot < 3; ++ot) acc2[ot] = {0.f, 0.f, 0.f, 0.f};
    {
        const int row = w * 16 + l15;
        bf16x8 C2[2][3]; bf16x8 A2[2];
        #pragma unroll
        for (int ot = 0; ot < 3; ++ot)
            C2[0][ot] = *(const bf16x8*)(l2t + ((size_t)(ot * 12) * 64 + lane) * 8);
        A2[0] = *(const bf16x8*)(lds + row * 768 + ((lg * 16) ^ ((row & 7) << 4)));
        #pragma unroll
        for (int ks = 0; ks < 12; ++ks) {
            int cur = ks & 1, nxt = cur ^ 1;
            if (ks < 11) {
                #pragma unroll
                for (int ot = 0; ot < 3; ++ot)
                    C2[nxt][ot] = *(const bf16x8*)(l2t + ((size_t)(ot * 12 + ks + 1) * 64 + lane) * 8);
                A2[nxt] = *(const bf16x8*)(lds + row * 768 + (((ks + 1) * 64 + lg * 16) ^ ((row & 7) << 4)));
            }
            #pragma unroll
            for (int ot = 0; ot < 3; ++ot)
                acc2[ot] = __builtin_amdgcn_mfma_f32_16x16x32_bf16(A2[cur], C2[cur][ot], acc2[ot], 0, 0, 0);
        }
    }

    // bias + log_softmax over 40 classes (row spread over 16 lanes x 3 regs)
    int c0 = l15;
    #pragma unroll
    for (int r = 0; r < 4; ++r) {
        float v0 = acc2[0][r] + l2b[c0];
        float v1 = acc2[1][r] + l2b[c0 + 16];
        float v2 = (c0 < 8) ? (acc2[2][r] + l2b[c0 + 32]) : -1e30f;
        float mx = fmaxf(fmaxf(v0, v1), v2);
        for (int msk = 1; msk < 16; msk <<= 1) mx = fmaxf(mx, __shfl_xor(mx, msk));
        float s = __expf(v0 - mx) + __expf(v1 - mx) + ((c0 < 8) ? __expf(v2 - mx) : 0.f);
        for (int msk = 1; msk < 16; msk <<= 1) s += __shfl_xor(s, msk);
        float lse = mx + __logf(s);
        int node = nbase + w * 16 + lg * 4 + r;
        if (node < N_NODES) {
            out[(size_t)node * 40 + c0] = v0 - lse;
            out[(size_t)node * 40 + c0 + 16] = v1 - lse;
            if (c0 < 8) out[(size_t)node * 40 + c0 + 32] = v2 - lse;
        }
    }
}

extern "C" void kernel_launch(void* const* d_in, const int* in_sizes, int n_in,
                              void* d_out, int out_size, void* d_ws, size_t ws_size,
                              hipStream_t stream) {
    const float* x  = (const float*)d_in[0];
    const int*   ei = (const int*)d_in[1];
    const float* gw1[3] = {(const float*)d_in[2],  (const float*)d_in[6],  (const float*)d_in[10]};
    const float* gb1[3] = {(const float*)d_in[3],  (const float*)d_in[7],  (const float*)d_in[11]};
    const float* gw2[3] = {(const float*)d_in[4],  (const float*)d_in[8],  (const float*)d_in[12]};
    const float* gb2[3] = {(const float*)d_in[5],  (const float*)d_in[9],  (const float*)d_in[13]};
    const float* l1w = (const float*)d_in[14];
    const float* l1b = (const float*)d_in[15];
    const float* l2w = (const float*)d_in[16];
    const float* l2b = (const float*)d_in[17];
    float* out = (float*)d_out;

    char* p = (char*)d_ws;
    auto alloc = [&](size_t bytes) { char* q = p; p += (bytes + 255) & ~(size_t)255; return q; };
    int* rp   = (int*)alloc(4 * (N_NODES + 1));
    int* cnt  = (int*)alloc(4 * N_NODES);
    int* bsum = (int*)alloc(4 * 256);
    int* colv = (int*)alloc(4 * (size_t)NEDGE);
    unsigned short* t  = (unsigned short*)alloc(2 * (size_t)N_NODES * 128);
    unsigned short* h1 = (unsigned short*)alloc(2 * (size_t)N_NODES * 128);
    unsigned short* h2 = (unsigned short*)alloc(2 * (size_t)N_NODES * 128);
    unsigned short* h3 = (unsigned short*)alloc(2 * (size_t)N_NODES * 128);
    unsigned short* xs = h3;   // alias: xs dead after layer-1 agg, h3 written in layer 3
    unsigned short* wt[6];
    for (int i = 0; i < 6; ++i) wt[i] = (unsigned short*)alloc(2 * 128 * 128);
    unsigned short* l1t = (unsigned short*)alloc(2 * 384 * 384);
    unsigned short* l2t = (unsigned short*)alloc(2 * 48 * 384);

    const int nb = (N_NODES + 1023) / 1024;     // 98
    // CSR build
    k_zero<<<(N_NODES + 255) / 256, 256, 0, stream>>>(cnt, N_NODES);
    k_count<<<(NEDGE + 255) / 256, 256, 0, stream>>>(ei, cnt);
    k_scan1<<<nb, 256, 0, stream>>>(cnt, rp, bsum);
    k_scan2<<<1, 256, 0, stream>>>(bsum, nb);
    k_scan3<<<nb, 256, 0, stream>>>(rp, bsum);
    k_zero<<<(N_NODES + 255) / 256, 256, 0, stream>>>(cnt, N_NODES);
    k_fillr<<<((NEDGE + 255) / 256) * FILL_SLICES, 256, 0, stream>>>(ei, rp, cnt, colv);

    // weight prep (fragment-major bf16)
    for (int i = 0; i < 3; ++i) {
        k_wprep<<<(128 * 128 + 255) / 256, 256, 0, stream>>>(gw1[i], wt[2 * i], 128, 128, 128);
        k_wprep<<<(128 * 128 + 255) / 256, 256, 0, stream>>>(gw2[i], wt[2 * i + 1], 128, 128, 128);
    }
    k_wprep<<<(384 * 384 + 255) / 256, 256, 0, stream>>>(l1w, l1t, 384, 384, 384);
    k_wprep<<<(384 * 48 + 255) / 256, 256, 0, stream>>>(l2w, l2t, 384, 40, 48);

    // x -> sliced bf16
    k_xprep<<<8 * ((N_NODES * 8 + 255) / 256), 256, 0, stream>>>(x, xs);

    const int gagg = ((N_NODES + AGG_NODES - 1) / AGG_NODES) * 8;
    const int gtile = (N_NODES + 63) / 64;
    // layer 1
    k_aggs<<<gagg, 256, 0, stream>>>(xs, t, rp, colv);
    k_mlp<<<gtile, 256, 0, stream>>>(t, wt[0], gb1[0], wt[1], gb2[0], h1);
    // layer 2
    k_aggs<<<gagg, 256, 0, stream>>>(h1, t, rp, colv);
    k_mlp<<<gtile, 256, 0, stream>>>(t, wt[2], gb1[1], wt[3], gb2[1], h2);
    // layer 3
    k_aggs<<<gagg, 256, 0, stream>>>(h2, t, rp, colv);
    k_mlp<<<gtile, 256, 0, stream>>>(t, wt[4], gb1[2], wt[5], gb2[2], h3);
    // head
    k_final<<<gtile, 256, 0, stream>>>(h1, h2, h3, l1t, l1b, l2t, l2b, out);
}

// Round 7
// 520.555 us; speedup vs baseline: 1.8321x; 1.0035x over previous
//
#include <hip/hip_runtime.h>

#define N_NODES 100000
#define NEDGE   1600000
#define NHID    128
#define NCLASS  40

#define AGG_NODES 128
#define COLV_LDS  3072
#define FILL_SLICES 8
#define FILL_RANGE  12500   // N_NODES / FILL_SLICES

using bf16x8 = __attribute__((ext_vector_type(8))) short;
using f32x4  = __attribute__((ext_vector_type(4))) float;

__device__ __forceinline__ float bf2f(unsigned short s) {
    unsigned u = ((unsigned)s) << 16; float f; __builtin_memcpy(&f, &u, 4); return f;
}
__device__ __forceinline__ unsigned short f2bf(float f) {
    unsigned u; __builtin_memcpy(&u, &f, 4);
    u = u + 0x7fffu + ((u >> 16) & 1u);          // RNE
    return (unsigned short)(u >> 16);
}

// global -> LDS direct (16B/lane). Dest: wave-uniform base + lane*16 (linear).
// Source: per-lane address (pre-swizzled to match swizzled LDS reader).
__device__ __forceinline__ void gld16(const void* g, void* l) {
    __builtin_amdgcn_global_load_lds(g, l, 16, 0, 0);
}

// ---------------- CSR build ----------------
__global__ void k_zero(int* __restrict__ p, int n) {
    int i = blockIdx.x * 256 + threadIdx.x;
    if (i < n) p[i] = 0;
}

__global__ void k_count(const int* __restrict__ ei, int* __restrict__ cnt) {
    int e = blockIdx.x * 256 + threadIdx.x;
    if (e < NEDGE) atomicAdd(&cnt[ei[NEDGE + e]], 1);   // dst row of edge_index
}

// block scans 1024 elements (256 thr x 4)
__global__ void k_scan1(const int* __restrict__ cnt, int* __restrict__ rp, int* __restrict__ bsum) {
    __shared__ int sh[256];
    int t = threadIdx.x, base = blockIdx.x * 1024;
    int v[4]; int s = 0;
    for (int k = 0; k < 4; ++k) { int i = base + t * 4 + k; v[k] = (i < N_NODES) ? cnt[i] : 0; s += v[k]; }
    sh[t] = s; __syncthreads();
    for (int off = 1; off < 256; off <<= 1) {
        int x = (t >= off) ? sh[t - off] : 0;
        __syncthreads();
        sh[t] += x;
        __syncthreads();
    }
    int excl = sh[t] - s;
    for (int k = 0; k < 4; ++k) { int i = base + t * 4 + k; if (i < N_NODES) rp[i] = excl; excl += v[k]; }
    if (t == 255) bsum[blockIdx.x] = sh[255];
}

__global__ void k_scan2(int* __restrict__ bsum, int nb) {
    __shared__ int sh[256];
    int t = threadIdx.x;
    int v = (t < nb) ? bsum[t] : 0;
    sh[t] = v; __syncthreads();
    for (int off = 1; off < 256; off <<= 1) {
        int x = (t >= off) ? sh[t - off] : 0;
        __syncthreads();
        sh[t] += x;
        __syncthreads();
    }
    if (t < nb) bsum[t] = sh[t] - v;   // exclusive block offsets
}

__global__ void k_scan3(int* __restrict__ rp, const int* __restrict__ bsum) {
    int base = blockIdx.x * 1024;
    int off = bsum[blockIdx.x];
    for (int k = 0; k < 4; ++k) {
        int i = base + threadIdx.x * 4 + k;
        if (i < N_NODES) rp[i] += off;
    }
    if (blockIdx.x == 0 && threadIdx.x == 0) rp[N_NODES] = NEDGE;
}

// range-partitioned fill: slice = blockIdx&7 owns dst in [slice*12500,(slice+1)*12500).
__global__ __launch_bounds__(256) void k_fillr(const int* __restrict__ ei, const int* __restrict__ rp,
                                               int* __restrict__ cur, int* __restrict__ colv) {
    int slice = blockIdx.x & 7;
    int e = (blockIdx.x >> 3) * 256 + threadIdx.x;
    if (e >= NEDGE) return;
    int d = ei[NEDGE + e];
    int lo = slice * FILL_RANGE;
    if (d >= lo && d < lo + FILL_RANGE) {
        int p = atomicAdd(&cur[d], 1);
        colv[rp[d] + p] = ei[e];
    }
}

// ---------------- weight prep: fragment-major bf16 layout ----------------
// wt[((ot*KS + ks)*64 + lane)*8 + e] = w[k][c],  c = ot*16 + (lane&15),
// k = ks*32 + (lane>>4)*8 + e.  One B-fragment load = 64 lanes x contiguous 16B.
__global__ void k_wprep(const float* __restrict__ w, unsigned short* __restrict__ wt,
                        int K, int O, int Opad) {
    int idx = blockIdx.x * 256 + threadIdx.x;
    if (idx >= K * Opad) return;
    int kss = K >> 5;
    int e = idx & 7, lane = (idx >> 3) & 63, rest = idx >> 9;
    int ks = rest % kss, ot = rest / kss;
    int c = ot * 16 + (lane & 15);
    int k = ks * 32 + (lane >> 4) * 8 + e;
    float v = (c < O) ? w[k * O + c] : 0.f;
    wt[idx] = f2bf(v);
}

// ---------------- x -> sliced bf16 layout [8][N][16] ----------------
__global__ void k_xprep(const float* __restrict__ x, unsigned short* __restrict__ xs) {
    int s = blockIdx.x & 7;
    int rest = (blockIdx.x >> 3) * 256 + threadIdx.x;   // word index within slice, N*8 words
    if (rest >= N_NODES * 8) return;
    int n = rest >> 3, wrd = rest & 7;
    float2 v = *(const float2*)(x + (size_t)n * 128 + s * 16 + wrd * 2);
    ((unsigned*)xs)[(size_t)s * N_NODES * 8 + rest] =
        (unsigned)f2bf(v.x) | ((unsigned)f2bf(v.y) << 16);
}

// ---------------- aggregation, sliced + LDS colv + 8-deep gather MLP ----------------
__device__ __forceinline__ void acc8(float* acc, uint4 f, float m) {
    unsigned u[4] = {f.x, f.y, f.z, f.w};
    for (int d = 0; d < 4; ++d) {
        acc[2 * d]     = fmaf(m, bf2f((unsigned short)u[d]), acc[2 * d]);
        acc[2 * d + 1] = fmaf(m, bf2f((unsigned short)(u[d] >> 16)), acc[2 * d + 1]);
    }
}

__global__ __launch_bounds__(256) void k_aggs(const unsigned short* __restrict__ feat,
                                              unsigned short* __restrict__ tout,
                                              const int* __restrict__ rp,
                                              const int* __restrict__ colv) {
    __shared__ int scol[COLV_LDS];
    __shared__ int srp[AGG_NODES + 1];
    const int s = blockIdx.x & 7;
    const int chunk = blockIdx.x >> 3;
    const int tid = threadIdx.x;
    const int nbase = chunk * AGG_NODES;

    for (int i = tid; i <= AGG_NODES; i += 256) {
        int n = nbase + i;
        srp[i] = rp[n <= N_NODES ? n : N_NODES];
    }
    __syncthreads();
    const int ebase = srp[0];
    const int ecount = srp[AGG_NODES] - ebase;
    const int elds = ecount < COLV_LDS ? ecount : COLV_LDS;
    for (int i = tid; i < elds; i += 256) scol[i] = colv[ebase + i];
    __syncthreads();

    const unsigned* fs = (const unsigned*)feat + (size_t)s * N_NODES * 8;
    unsigned* ts = (unsigned*)tout + (size_t)s * N_NODES * 8;

    const int sub = tid >> 1, half = tid & 1;
    const int node = nbase + sub;
    if (node >= N_NODES) return;
    const int off = half * 4;
    const int e0 = srp[sub] - ebase, e1 = srp[sub + 1] - ebase;

    float acc[8];
    {
        uint4 a = *(const uint4*)(fs + (size_t)node * 8 + off);
        unsigned u[4] = {a.x, a.y, a.z, a.w};
        for (int d = 0; d < 4; ++d) {
            acc[2 * d]     = bf2f((unsigned short)u[d]);
            acc[2 * d + 1] = bf2f((unsigned short)(u[d] >> 16));
        }
    }

    for (int e = e0; e < e1; e += 8) {
        int j[8]; float m[8];
        #pragma unroll
        for (int k = 0; k < 8; ++k) {
            int ee = e + k;
            bool v = ee < e1;
            int idx = ee < COLV_LDS ? scol[ee] : colv[ebase + ee];
            j[k] = v ? idx : node;
            m[k] = v ? 1.f : 0.f;
        }
        uint4 f[8];
        #pragma unroll
        for (int k = 0; k < 8; ++k)
            f[k] = *(const uint4*)(fs + (size_t)j[k] * 8 + off);
        #pragma unroll
        for (int k = 0; k < 8; ++k) acc8(acc, f[k], m[k]);
    }

    uint4 o;
    o.x = (unsigned)f2bf(acc[0]) | ((unsigned)f2bf(acc[1]) << 16);
    o.y = (unsigned)f2bf(acc[2]) | ((unsigned)f2bf(acc[3]) << 16);
    o.z = (unsigned)f2bf(acc[4]) | ((unsigned)f2bf(acc[5]) << 16);
    o.w = (unsigned)f2bf(acc[6]) | ((unsigned)f2bf(acc[7]) << 16);
    *(uint4*)(ts + (size_t)node * 8 + off) = o;
}

// ---------------- fused GIN MLP: h = relu(relu(t@w1+b1)@w2+b2), 64-node tile ----------------
__global__ __launch_bounds__(256) void k_mlp(
    const unsigned short* __restrict__ tin,
    const unsigned short* __restrict__ w1t, const float* __restrict__ b1,
    const unsigned short* __restrict__ w2t, const float* __restrict__ b2,
    unsigned short* __restrict__ hout) {
    __shared__ __align__(16) char tlds[64 * 256];
    __shared__ __align__(16) char hlds[64 * 256];
    const int tid = threadIdx.x, lane = tid & 63, w = tid >> 6;
    const int l15 = lane & 15, lg = lane >> 4;
    const int nbase = blockIdx.x * 64;

    // stage t tile: 4 x 1KB wave-loads, direct to LDS
    #pragma unroll
    for (int i = 0; i < 4; ++i) {
        int byte = w * 4096 + i * 1024 + lane * 16;
        int r = byte >> 8, c8s = (byte >> 4) & 15;
        int c8 = c8s ^ (r & 7);
        int slice = c8 >> 1, half = c8 & 1;
        int node = nbase + r; if (node >= N_NODES) node = 0;
        gld16(tin + ((size_t)slice * N_NODES + node) * 16 + half * 8,
              tlds + w * 4096 + i * 1024);
    }

    // preload B1 fragments + bias (wave w owns out cols [32w, 32w+32))
    bf16x8 B1[2][4]; float bias1[2]; int cols[2];
    #pragma unroll
    for (int ot = 0; ot < 2; ++ot) {
        int c = (w * 2 + ot) * 16 + l15;
        cols[ot] = c; bias1[ot] = b1[c];
        #pragma unroll
        for (int ks = 0; ks < 4; ++ks)
            B1[ot][ks] = *(const bf16x8*)(w1t + ((size_t)((w * 2 + ot) * 4 + ks) * 64 + lane) * 8);
    }
    __syncthreads();   // vmcnt(0) drains staging

    // GEMM1 -> relu -> hlds (A double-buffered over m)
    {
        bf16x8 A[2][4];
        #pragma unroll
        for (int ks = 0; ks < 4; ++ks)
            A[0][ks] = *(const bf16x8*)(tlds + l15 * 256 + ((ks * 64 + lg * 16) ^ ((l15 & 7) << 4)));
        #pragma unroll
        for (int m = 0; m < 4; ++m) {
            int cur = m & 1, nxt = cur ^ 1;
            if (m < 3) {
                int row = (m + 1) * 16 + l15;
                #pragma unroll
                for (int ks = 0; ks < 4; ++ks)
                    A[nxt][ks] = *(const bf16x8*)(tlds + row * 256 + ((ks * 64 + lg * 16) ^ ((row & 7) << 4)));
            }
            #pragma unroll
            for (int ot = 0; ot < 2; ++ot) {
                f32x4 acc = {0.f, 0.f, 0.f, 0.f};
                #pragma unroll
                for (int ks = 0; ks < 4; ++ks)
                    acc = __builtin_amdgcn_mfma_f32_16x16x32_bf16(A[cur][ks], B1[ot][ks], acc, 0, 0, 0);
                int c2 = cols[ot] * 2;
                #pragma unroll
                for (int r = 0; r < 4; ++r) {
                    int row = m * 16 + lg * 4 + r;
                    float v = acc[r] + bias1[ot]; v = v > 0.f ? v : 0.f;
                    *(unsigned short*)(hlds + row * 256 + (c2 ^ ((row & 7) << 4))) = f2bf(v);
                }
            }
        }
    }

    // preload B2
    bf16x8 B2[2][4]; float bias2[2];
    #pragma unroll
    for (int ot = 0; ot < 2; ++ot) {
        bias2[ot] = b2[cols[ot]];
        #pragma unroll
        for (int ks = 0; ks < 4; ++ks)
            B2[ot][ks] = *(const bf16x8*)(w2t + ((size_t)((w * 2 + ot) * 4 + ks) * 64 + lane) * 8);
    }
    __syncthreads();

    // GEMM2 -> relu -> global (sliced layout), A double-buffered over m
    {
        bf16x8 A[2][4];
        #pragma unroll
        for (int ks = 0; ks < 4; ++ks)
            A[0][ks] = *(const bf16x8*)(hlds + l15 * 256 + ((ks * 64 + lg * 16) ^ ((l15 & 7) << 4)));
        #pragma unroll
        for (int m = 0; m < 4; ++m) {
            int cur = m & 1, nxt = cur ^ 1;
            if (m < 3) {
                int row = (m + 1) * 16 + l15;
                #pragma unroll
                for (int ks = 0; ks < 4; ++ks)
                    A[nxt][ks] = *(const bf16x8*)(hlds + row * 256 + ((ks * 64 + lg * 16) ^ ((row & 7) << 4)));
            }
            #pragma unroll
            for (int ot = 0; ot < 2; ++ot) {
                f32x4 acc = {0.f, 0.f, 0.f, 0.f};
                #pragma unroll
                for (int ks = 0; ks < 4; ++ks)
                    acc = __builtin_amdgcn_mfma_f32_16x16x32_bf16(A[cur][ks], B2[ot][ks], acc, 0, 0, 0);
                int cslice = cols[ot] >> 4, cw = cols[ot] & 15;
                #pragma unroll
                for (int r = 0; r < 4; ++r) {
                    int node = nbase + m * 16 + lg * 4 + r;
                    if (node < N_NODES) {
                        float v = acc[r] + bias2[ot]; v = v > 0.f ? v : 0.f;
                        hout[((size_t)cslice * N_NODES + node) * 16 + cw] = f2bf(v);
                    }
                }
            }
        }
    }
}

// ---------------- fused head, M=128: relu(concat@lin1+b) @ lin2 + b -> log_softmax ----------
// 512 threads (8 waves), 128 nodes/block, 96KB dynamic LDS (A-tile then hidden).
// Wave w owns 48 lin1 out-cols (3 ot): 2x B-reuse vs M=64. l1t fragment-major (KS=12, 24 ot);
// l2t fragment-major (KS=12, 3 ot, cols padded to 48).
__global__ __launch_bounds__(512, 2) void k_final(
    const unsigned short* __restrict__ h1, const unsigned short* __restrict__ h2,
    const unsigned short* __restrict__ h3,
    const unsigned short* __restrict__ l1t, const float* __restrict__ l1b,
    const unsigned short* __restrict__ l2t, const float* __restrict__ l2b,
    float* __restrict__ out) {
    extern __shared__ __align__(16) char lds[];    // 128 * 768 = 96KB
    const int tid = threadIdx.x, lane = tid & 63, w = tid >> 6;
    const int l15 = lane & 15, lg = lane >> 4;
    const int nbase = blockIdx.x * 128;

    // stage concat(h1,h2,h3) tile: 12 x 1KB wave-loads direct to LDS per wave (96KB total)
    #pragma unroll
    for (int i = 0; i < 12; ++i) {
        unsigned byte = (unsigned)(w * 12288 + i * 1024 + lane * 16);
        unsigned r = byte / 768u;
        unsigned rem = byte - r * 768u;
        int c8 = (int)(rem >> 4) ^ (int)(r & 7);
        int part = c8 >> 4, c8p = c8 & 15;
        int slice = c8p >> 1, half = c8p & 1;
        int node = nbase + (int)r; if (node >= N_NODES) node = 0;
        const unsigned short* hp = part == 0 ? h1 : (part == 1 ? h2 : h3);
        gld16(hp + ((size_t)slice * N_NODES + node) * 16 + half * 8,
              lds + w * 12288 + i * 1024);
    }

    // preload lin1 B for ks=0 (wave w -> ot tiles w*3..w*3+3)
    bf16x8 B[2][3];
    #pragma unroll
    for (int ot = 0; ot < 3; ++ot)
        B[0][ot] = *(const bf16x8*)(l1t + ((size_t)((w * 3 + ot) * 12) * 64 + lane) * 8);
    __syncthreads();   // vmcnt(0) drains staging

    // lin1: wave w owns out cols [48w, 48w+48), 8 m-tiles; B double-buffered over ks
    f32x4 acc[8][3];
    #pragma unroll
    for (int m = 0; m < 8; ++m)
        #pragma unroll
        for (int ot = 0; ot < 3; ++ot) acc[m][ot] = {0.f, 0.f, 0.f, 0.f};
    {
        #pragma unroll
        for (int ks = 0; ks < 12; ++ks) {
            int cur = ks & 1, nxt = cur ^ 1;
            if (ks < 11) {
                #pragma unroll
                for (int ot = 0; ot < 3; ++ot)
                    B[nxt][ot] = *(const bf16x8*)(l1t + ((size_t)((w * 3 + ot) * 12 + ks + 1) * 64 + lane) * 8);
            }
            bf16x8 A[8];
            #pragma unroll
            for (int m = 0; m < 8; ++m) {
                int row = m * 16 + l15;
                A[m] = *(const bf16x8*)(lds + row * 768 + ((ks * 64 + lg * 16) ^ ((row & 7) << 4)));
            }
            #pragma unroll
            for (int ot = 0; ot < 3; ++ot)
                #pragma unroll
                for (int m = 0; m < 8; ++m)
                    acc[m][ot] = __builtin_amdgcn_mfma_f32_16x16x32_bf16(A[m], B[cur][ot], acc[m][ot], 0, 0, 0);
        }
    }
    __syncthreads();   // everyone done reading A-tile

    // relu + write hidden (bf16) into same LDS
    #pragma unroll
    for (int ot = 0; ot < 3; ++ot) {
        int c = (w * 3 + ot) * 16 + l15;
        float bias = l1b[c];
        #pragma unroll
        for (int m = 0; m < 8; ++m)
            #pragma unroll
            for (int r = 0; r < 4; ++r) {
                int row = m * 16 + lg * 4 + r;
                float v = acc[m][ot][r] + bias; v = v > 0.f ? v : 0.f;
                *(unsigned short*)(lds + row * 768 + ((c * 2) ^ ((row & 7) << 4))) = f2bf(v);
            }
    }
    __syncthreads();

    // lin2: wave w owns rows [16w, 16w+16); B+A double-buffered over ks
    f32x4 acc2[3];
    #pragma unroll
    for (int ot = 0; ot < 3; ++ot) acc2[ot] = {0.f, 0.f, 0.f, 0.f};
    {
        const int row = w * 16 + l15;
        bf16x8 C2[2][3]; bf16x8 A2[2];
        #pragma unroll
        for (int ot = 0; ot < 3; ++ot)
            C2[0][ot] = *(const bf16x8*)(l2t + ((size_t)(ot * 12) * 64 + lane) * 8);
        A2[0] = *(const bf16x8*)(lds + row * 768 + ((lg * 16) ^ ((row & 7) << 4)));
        #pragma unroll
        for (int ks = 0; ks < 12; ++ks) {
            int cur = ks & 1, nxt = cur ^ 1;
            if (ks < 11) {
                #pragma unroll
                for (int ot = 0; ot < 3; ++ot)
                    C2[nxt][ot] = *(const bf16x8*)(l2t + ((size_t)(ot * 12 + ks + 1) * 64 + lane) * 8);
                A2[nxt] = *(const bf16x8*)(lds + row * 768 + (((ks + 1) * 64 + lg * 16) ^ ((row & 7) << 4)));
            }
            #pragma unroll
            for (int ot = 0; ot < 3; ++ot)
                acc2[ot] = __builtin_amdgcn_mfma_f32_16x16x32_bf16(A2[cur], C2[cur][ot], acc2[ot], 0, 0, 0);
        }
    }

    // bias + log_softmax over 40 classes (row spread over 16 lanes x 3 regs)
    int c0 = l15;
    #pragma unroll
    for (int r = 0; r < 4; ++r) {
        float v0 = acc2[0][r] + l2b[c0];
        float v1 = acc2[1][r] + l2b[c0 + 16];
        float v2 = (c0 < 8) ? (acc2[2][r] + l2b[c0 + 32]) : -1e30f;
        float mx = fmaxf(fmaxf(v0, v1), v2);
        for (int msk = 1; msk < 16; msk <<= 1) mx = fmaxf(mx, __shfl_xor(mx, msk));
        float s = __expf(v0 - mx) + __expf(v1 - mx) + ((c0 < 8) ? __expf(v2 - mx) : 0.f);
        for (int msk = 1; msk < 16; msk <<= 1) s += __shfl_xor(s, msk);
        float lse = mx + __logf(s);
        int node = nbase + w * 16 + lg * 4 + r;
        if (node < N_NODES) {
            out[(size_t)node * 40 + c0] = v0 - lse;
            out[(size_t)node * 40 + c0 + 16] = v1 - lse;
            if (c0 < 8) out[(size_t)node * 40 + c0 + 32] = v2 - lse;
        }
    }
}

extern "C" void kernel_launch(void* const* d_in, const int* in_sizes, int n_in,
                              void* d_out, int out_size, void* d_ws, size_t ws_size,
                              hipStream_t stream) {
    const float* x  = (const float*)d_in[0];
    const int*   ei = (const int*)d_in[1];
    const float* gw1[3] = {(const float*)d_in[2],  (const float*)d_in[6],  (const float*)d_in[10]};
    const float* gb1[3] = {(const float*)d_in[3],  (const float*)d_in[7],  (const float*)d_in[11]};
    const float* gw2[3] = {(const float*)d_in[4],  (const float*)d_in[8],  (const float*)d_in[12]};
    const float* gb2[3] = {(const float*)d_in[5],  (const float*)d_in[9],  (const float*)d_in[13]};
    const float* l1w = (const float*)d_in[14];
    const float* l1b = (const float*)d_in[15];
    const float* l2w = (const float*)d_in[16];
    const float* l2b = (const float*)d_in[17];
    float* out = (float*)d_out;

    char* p = (char*)d_ws;
    auto alloc = [&](size_t bytes) { char* q = p; p += (bytes + 255) & ~(size_t)255; return q; };
    int* rp   = (int*)alloc(4 * (N_NODES + 1));
    int* cnt  = (int*)alloc(4 * N_NODES);
    int* bsum = (int*)alloc(4 * 256);
    int* colv = (int*)alloc(4 * (size_t)NEDGE);
    unsigned short* t  = (unsigned short*)alloc(2 * (size_t)N_NODES * 128);
    unsigned short* h1 = (unsigned short*)alloc(2 * (size_t)N_NODES * 128);
    unsigned short* h2 = (unsigned short*)alloc(2 * (size_t)N_NODES * 128);
    unsigned short* h3 = (unsigned short*)alloc(2 * (size_t)N_NODES * 128);
    unsigned short* xs = h3;   // alias: xs dead after layer-1 agg, h3 written in layer 3
    unsigned short* wt[6];
    for (int i = 0; i < 6; ++i) wt[i] = (unsigned short*)alloc(2 * 128 * 128);
    unsigned short* l1t = (unsigned short*)alloc(2 * 384 * 384);
    unsigned short* l2t = (unsigned short*)alloc(2 * 48 * 384);

    // allow 96KB dynamic LDS for k_final (host-side attr set; not a stream op)
    static bool attr_set = false;
    if (!attr_set) {
        hipFuncSetAttribute((const void*)k_final,
                            hipFuncAttributeMaxDynamicSharedMemorySize, 128 * 768);
        attr_set = true;
    }

    const int nb = (N_NODES + 1023) / 1024;     // 98
    // CSR build
    k_zero<<<(N_NODES + 255) / 256, 256, 0, stream>>>(cnt, N_NODES);
    k_count<<<(NEDGE + 255) / 256, 256, 0, stream>>>(ei, cnt);
    k_scan1<<<nb, 256, 0, stream>>>(cnt, rp, bsum);
    k_scan2<<<1, 256, 0, stream>>>(bsum, nb);
    k_scan3<<<nb, 256, 0, stream>>>(rp, bsum);
    k_zero<<<(N_NODES + 255) / 256, 256, 0, stream>>>(cnt, N_NODES);
    k_fillr<<<((NEDGE + 255) / 256) * FILL_SLICES, 256, 0, stream>>>(ei, rp, cnt, colv);

    // weight prep (fragment-major bf16)
    for (int i = 0; i < 3; ++i) {
        k_wprep<<<(128 * 128 + 255) / 256, 256, 0, stream>>>(gw1[i], wt[2 * i], 128, 128, 128);
        k_wprep<<<(128 * 128 + 255) / 256, 256, 0, stream>>>(gw2[i], wt[2 * i + 1], 128, 128, 128);
    }
    k_wprep<<<(384 * 384 + 255) / 256, 256, 0, stream>>>(l1w, l1t, 384, 384, 384);
    k_wprep<<<(384 * 48 + 255) / 256, 256, 0, stream>>>(l2w, l2t, 384, 40, 48);

    // x -> sliced bf16
    k_xprep<<<8 * ((N_NODES * 8 + 255) / 256), 256, 0, stream>>>(x, xs);

    const int gagg = ((N_NODES + AGG_NODES - 1) / AGG_NODES) * 8;
    const int gtile = (N_NODES + 63) / 64;
    const int gtile2 = (N_NODES + 127) / 128;
    // layer 1
    k_aggs<<<gagg, 256, 0, stream>>>(xs, t, rp, colv);
    k_mlp<<<gtile, 256, 0, stream>>>(t, wt[0], gb1[0], wt[1], gb2[0], h1);
    // layer 2
    k_aggs<<<gagg, 256, 0, stream>>>(h1, t, rp, colv);
    k_mlp<<<gtile, 256, 0, stream>>>(t, wt[2], gb1[1], wt[3], gb2[1], h2);
    // layer 3
    k_aggs<<<gagg, 256, 0, stream>>>(h2, t, rp, colv);
    k_mlp<<<gtile, 256, 0, stream>>>(t, wt[4], gb1[2], wt[5], gb2[2], h3);
    // head
    k_final<<<gtile2, 512, 128 * 768, stream>>>(h1, h2, h3, l1t, l1b, l2t, l2b, out);
}

// Round 8
// 508.297 us; speedup vs baseline: 1.8762x; 1.0241x over previous
//
#include <hip/hip_runtime.h>

#define N_NODES 100000
#define NEDGE   1600000
#define NHID    128
#define NCLASS  40

#define AGG_NODES 128
#define COLV_LDS  3072
#define FILL_SLICES 8
#define FILL_RANGE  12500   // N_NODES / FILL_SLICES
#define WPREP_TOT   264192  // 6*16384 + 147456 + 18432

using bf16x8 = __attribute__((ext_vector_type(8))) short;
using f32x4  = __attribute__((ext_vector_type(4))) float;

__device__ __forceinline__ float bf2f(unsigned short s) {
    unsigned u = ((unsigned)s) << 16; float f; __builtin_memcpy(&f, &u, 4); return f;
}
__device__ __forceinline__ unsigned short f2bf(float f) {
    unsigned u; __builtin_memcpy(&u, &f, 4);
    u = u + 0x7fffu + ((u >> 16) & 1u);          // RNE
    return (unsigned short)(u >> 16);
}

// global -> LDS direct (16B/lane). Dest: wave-uniform base + lane*16 (linear).
// Source: per-lane address (pre-swizzled to match swizzled LDS reader).
__device__ __forceinline__ void gld16(const void* g, void* l) {
    __builtin_amdgcn_global_load_lds(g, l, 16, 0, 0);
}

// ---------------- CSR build ----------------
__global__ void k_zero(int* __restrict__ p, int n) {
    int i = blockIdx.x * 256 + threadIdx.x;
    if (i < n) p[i] = 0;
}

// range-partitioned count: slice owns dst in [slice*FILL_RANGE, ...+FILL_RANGE).
// Atomic lines stay XCD-local (same mechanism as k_fillr's R5 win).
__global__ __launch_bounds__(256) void k_countr(const int* __restrict__ ei, int* __restrict__ cnt) {
    int slice = blockIdx.x & 7;
    int e = (blockIdx.x >> 3) * 256 + threadIdx.x;
    if (e >= NEDGE) return;
    int d = ei[NEDGE + e];
    int lo = slice * FILL_RANGE;
    if (d >= lo && d < lo + FILL_RANGE) atomicAdd(&cnt[d], 1);
}

// block scans 1024 elements (256 thr x 4)
__global__ void k_scan1(const int* __restrict__ cnt, int* __restrict__ rp, int* __restrict__ bsum) {
    __shared__ int sh[256];
    int t = threadIdx.x, base = blockIdx.x * 1024;
    int v[4]; int s = 0;
    for (int k = 0; k < 4; ++k) { int i = base + t * 4 + k; v[k] = (i < N_NODES) ? cnt[i] : 0; s += v[k]; }
    sh[t] = s; __syncthreads();
    for (int off = 1; off < 256; off <<= 1) {
        int x = (t >= off) ? sh[t - off] : 0;
        __syncthreads();
        sh[t] += x;
        __syncthreads();
    }
    int excl = sh[t] - s;
    for (int k = 0; k < 4; ++k) { int i = base + t * 4 + k; if (i < N_NODES) rp[i] = excl; excl += v[k]; }
    if (t == 255) bsum[blockIdx.x] = sh[255];
}

__global__ void k_scan2(int* __restrict__ bsum, int nb) {
    __shared__ int sh[256];
    int t = threadIdx.x;
    int v = (t < nb) ? bsum[t] : 0;
    sh[t] = v; __syncthreads();
    for (int off = 1; off < 256; off <<= 1) {
        int x = (t >= off) ? sh[t - off] : 0;
        __syncthreads();
        sh[t] += x;
        __syncthreads();
    }
    if (t < nb) bsum[t] = sh[t] - v;   // exclusive block offsets
}

__global__ void k_scan3(int* __restrict__ rp, const int* __restrict__ bsum) {
    int base = blockIdx.x * 1024;
    int off = bsum[blockIdx.x];
    for (int k = 0; k < 4; ++k) {
        int i = base + threadIdx.x * 4 + k;
        if (i < N_NODES) rp[i] += off;
    }
    if (blockIdx.x == 0 && threadIdx.x == 0) rp[N_NODES] = NEDGE;
}

// range-partitioned fill: slice = blockIdx&7 owns dst in [slice*12500,(slice+1)*12500).
__global__ __launch_bounds__(256) void k_fillr(const int* __restrict__ ei, const int* __restrict__ rp,
                                               int* __restrict__ cur, int* __restrict__ colv) {
    int slice = blockIdx.x & 7;
    int e = (blockIdx.x >> 3) * 256 + threadIdx.x;
    if (e >= NEDGE) return;
    int d = ei[NEDGE + e];
    int lo = slice * FILL_RANGE;
    if (d >= lo && d < lo + FILL_RANGE) {
        int p = atomicAdd(&cur[d], 1);
        colv[rp[d] + p] = ei[e];
    }
}

// ---------------- weight prep: ALL weights in one dispatch, fragment-major bf16 ----------------
// dst regions contiguous from wtbase: 6x(128x128) | l1 (384x384) | l2 (384x48 padded).
// wt[((ot*KS + ks)*64 + lane)*8 + e] = w[k][c], c = ot*16+(lane&15), k = ks*32+(lane>>4)*8+e.
__global__ void k_wprep_all(const float* __restrict__ g0, const float* __restrict__ g1,
                            const float* __restrict__ g2, const float* __restrict__ g3,
                            const float* __restrict__ g4, const float* __restrict__ g5,
                            const float* __restrict__ l1w, const float* __restrict__ l2w,
                            unsigned short* __restrict__ dst) {
    int idx = blockIdx.x * 256 + threadIdx.x;
    if (idx >= WPREP_TOT) return;
    const float* w; int local, K, O;
    if (idx < 98304) {
        int r = idx >> 14; local = idx & 16383; K = 128; O = 128;
        w = r == 0 ? g0 : r == 1 ? g1 : r == 2 ? g2 : r == 3 ? g3 : r == 4 ? g4 : g5;
    } else if (idx < 245760) {
        local = idx - 98304; K = 384; O = 384; w = l1w;
    } else {
        local = idx - 245760; K = 384; O = 40; w = l2w;
    }
    int kss = K >> 5;
    int e = local & 7, lane = (local >> 3) & 63, rest = local >> 9;
    int ks = rest % kss, ot = rest / kss;
    int c = ot * 16 + (lane & 15);
    int k = ks * 32 + (lane >> 4) * 8 + e;
    float v = (c < O) ? w[k * O + c] : 0.f;
    dst[idx] = f2bf(v);
}

// ---------------- x -> sliced bf16 layout [8][N][16] ----------------
__global__ void k_xprep(const float* __restrict__ x, unsigned short* __restrict__ xs) {
    int s = blockIdx.x & 7;
    int rest = (blockIdx.x >> 3) * 256 + threadIdx.x;   // word index within slice, N*8 words
    if (rest >= N_NODES * 8) return;
    int n = rest >> 3, wrd = rest & 7;
    float2 v = *(const float2*)(x + (size_t)n * 128 + s * 16 + wrd * 2);
    ((unsigned*)xs)[(size_t)s * N_NODES * 8 + rest] =
        (unsigned)f2bf(v.x) | ((unsigned)f2bf(v.y) << 16);
}

// ---------------- aggregation, sliced + LDS colv + 8-deep gather MLP ----------------
__device__ __forceinline__ void acc8(float* acc, uint4 f, float m) {
    unsigned u[4] = {f.x, f.y, f.z, f.w};
    for (int d = 0; d < 4; ++d) {
        acc[2 * d]     = fmaf(m, bf2f((unsigned short)u[d]), acc[2 * d]);
        acc[2 * d + 1] = fmaf(m, bf2f((unsigned short)(u[d] >> 16)), acc[2 * d + 1]);
    }
}

__global__ __launch_bounds__(256) void k_aggs(const unsigned short* __restrict__ feat,
                                              unsigned short* __restrict__ tout,
                                              const int* __restrict__ rp,
                                              const int* __restrict__ colv) {
    __shared__ int scol[COLV_LDS];
    __shared__ int srp[AGG_NODES + 1];
    const int s = blockIdx.x & 7;
    const int chunk = blockIdx.x >> 3;
    const int tid = threadIdx.x;
    const int nbase = chunk * AGG_NODES;

    for (int i = tid; i <= AGG_NODES; i += 256) {
        int n = nbase + i;
        srp[i] = rp[n <= N_NODES ? n : N_NODES];
    }
    __syncthreads();
    const int ebase = srp[0];
    const int ecount = srp[AGG_NODES] - ebase;
    const int elds = ecount < COLV_LDS ? ecount : COLV_LDS;
    for (int i = tid; i < elds; i += 256) scol[i] = colv[ebase + i];
    __syncthreads();

    const unsigned* fs = (const unsigned*)feat + (size_t)s * N_NODES * 8;
    unsigned* ts = (unsigned*)tout + (size_t)s * N_NODES * 8;

    const int sub = tid >> 1, half = tid & 1;
    const int node = nbase + sub;
    if (node >= N_NODES) return;
    const int off = half * 4;
    const int e0 = srp[sub] - ebase, e1 = srp[sub + 1] - ebase;

    float acc[8];
    {
        uint4 a = *(const uint4*)(fs + (size_t)node * 8 + off);
        unsigned u[4] = {a.x, a.y, a.z, a.w};
        for (int d = 0; d < 4; ++d) {
            acc[2 * d]     = bf2f((unsigned short)u[d]);
            acc[2 * d + 1] = bf2f((unsigned short)(u[d] >> 16));
        }
    }

    for (int e = e0; e < e1; e += 8) {
        int j[8]; float m[8];
        #pragma unroll
        for (int k = 0; k < 8; ++k) {
            int ee = e + k;
            bool v = ee < e1;
            int idx = ee < COLV_LDS ? scol[ee] : colv[ebase + ee];
            j[k] = v ? idx : node;
            m[k] = v ? 1.f : 0.f;
        }
        uint4 f[8];
        #pragma unroll
        for (int k = 0; k < 8; ++k)
            f[k] = *(const uint4*)(fs + (size_t)j[k] * 8 + off);
        #pragma unroll
        for (int k = 0; k < 8; ++k) acc8(acc, f[k], m[k]);
    }

    uint4 o;
    o.x = (unsigned)f2bf(acc[0]) | ((unsigned)f2bf(acc[1]) << 16);
    o.y = (unsigned)f2bf(acc[2]) | ((unsigned)f2bf(acc[3]) << 16);
    o.z = (unsigned)f2bf(acc[4]) | ((unsigned)f2bf(acc[5]) << 16);
    o.w = (unsigned)f2bf(acc[6]) | ((unsigned)f2bf(acc[7]) << 16);
    *(uint4*)(ts + (size_t)node * 8 + off) = o;
}

// ---------------- fused GIN MLP: h = relu(relu(t@w1+b1)@w2+b2), 64-node tile ----------------
__global__ __launch_bounds__(256) void k_mlp(
    const unsigned short* __restrict__ tin,
    const unsigned short* __restrict__ w1t, const float* __restrict__ b1,
    const unsigned short* __restrict__ w2t, const float* __restrict__ b2,
    unsigned short* __restrict__ hout) {
    __shared__ __align__(16) char tlds[64 * 256];
    __shared__ __align__(16) char hlds[64 * 256];
    const int tid = threadIdx.x, lane = tid & 63, w = tid >> 6;
    const int l15 = lane & 15, lg = lane >> 4;
    const int nbase = blockIdx.x * 64;

    // stage t tile: 4 x 1KB wave-loads, direct to LDS
    #pragma unroll
    for (int i = 0; i < 4; ++i) {
        int byte = w * 4096 + i * 1024 + lane * 16;
        int r = byte >> 8, c8s = (byte >> 4) & 15;
        int c8 = c8s ^ (r & 7);
        int slice = c8 >> 1, half = c8 & 1;
        int node = nbase + r; if (node >= N_NODES) node = 0;
        gld16(tin + ((size_t)slice * N_NODES + node) * 16 + half * 8,
              tlds + w * 4096 + i * 1024);
    }

    // preload B1 AND B2 fragments + biases before the barrier: B2 is consumed only
    // after GEMM1, so its L2 latency hides behind GEMM1 compute.
    bf16x8 B1[2][4]; float bias1[2]; int cols[2];
    #pragma unroll
    for (int ot = 0; ot < 2; ++ot) {
        int c = (w * 2 + ot) * 16 + l15;
        cols[ot] = c; bias1[ot] = b1[c];
        #pragma unroll
        for (int ks = 0; ks < 4; ++ks)
            B1[ot][ks] = *(const bf16x8*)(w1t + ((size_t)((w * 2 + ot) * 4 + ks) * 64 + lane) * 8);
    }
    bf16x8 B2[2][4]; float bias2[2];
    #pragma unroll
    for (int ot = 0; ot < 2; ++ot) {
        bias2[ot] = b2[(w * 2 + ot) * 16 + l15];
        #pragma unroll
        for (int ks = 0; ks < 4; ++ks)
            B2[ot][ks] = *(const bf16x8*)(w2t + ((size_t)((w * 2 + ot) * 4 + ks) * 64 + lane) * 8);
    }
    __syncthreads();   // vmcnt(0) drains staging

    // GEMM1 -> relu -> hlds (A double-buffered over m)
    {
        bf16x8 A[2][4];
        #pragma unroll
        for (int ks = 0; ks < 4; ++ks)
            A[0][ks] = *(const bf16x8*)(tlds + l15 * 256 + ((ks * 64 + lg * 16) ^ ((l15 & 7) << 4)));
        #pragma unroll
        for (int m = 0; m < 4; ++m) {
            int cur = m & 1, nxt = cur ^ 1;
            if (m < 3) {
                int row = (m + 1) * 16 + l15;
                #pragma unroll
                for (int ks = 0; ks < 4; ++ks)
                    A[nxt][ks] = *(const bf16x8*)(tlds + row * 256 + ((ks * 64 + lg * 16) ^ ((row & 7) << 4)));
            }
            #pragma unroll
            for (int ot = 0; ot < 2; ++ot) {
                f32x4 acc = {0.f, 0.f, 0.f, 0.f};
                #pragma unroll
                for (int ks = 0; ks < 4; ++ks)
                    acc = __builtin_amdgcn_mfma_f32_16x16x32_bf16(A[cur][ks], B1[ot][ks], acc, 0, 0, 0);
                int c2 = cols[ot] * 2;
                #pragma unroll
                for (int r = 0; r < 4; ++r) {
                    int row = m * 16 + lg * 4 + r;
                    float v = acc[r] + bias1[ot]; v = v > 0.f ? v : 0.f;
                    *(unsigned short*)(hlds + row * 256 + (c2 ^ ((row & 7) << 4))) = f2bf(v);
                }
            }
        }
    }
    __syncthreads();

    // GEMM2 -> relu -> global (sliced layout), A double-buffered over m
    {
        bf16x8 A[2][4];
        #pragma unroll
        for (int ks = 0; ks < 4; ++ks)
            A[0][ks] = *(const bf16x8*)(hlds + l15 * 256 + ((ks * 64 + lg * 16) ^ ((l15 & 7) << 4)));
        #pragma unroll
        for (int m = 0; m < 4; ++m) {
            int cur = m & 1, nxt = cur ^ 1;
            if (m < 3) {
                int row = (m + 1) * 16 + l15;
                #pragma unroll
                for (int ks = 0; ks < 4; ++ks)
                    A[nxt][ks] = *(const bf16x8*)(hlds + row * 256 + ((ks * 64 + lg * 16) ^ ((row & 7) << 4)));
            }
            #pragma unroll
            for (int ot = 0; ot < 2; ++ot) {
                f32x4 acc = {0.f, 0.f, 0.f, 0.f};
                #pragma unroll
                for (int ks = 0; ks < 4; ++ks)
                    acc = __builtin_amdgcn_mfma_f32_16x16x32_bf16(A[cur][ks], B2[ot][ks], acc, 0, 0, 0);
                int cslice = cols[ot] >> 4, cw = cols[ot] & 15;
                #pragma unroll
                for (int r = 0; r < 4; ++r) {
                    int node = nbase + m * 16 + lg * 4 + r;
                    if (node < N_NODES) {
                        float v = acc[r] + bias2[ot]; v = v > 0.f ? v : 0.f;
                        hout[((size_t)cslice * N_NODES + node) * 16 + cw] = f2bf(v);
                    }
                }
            }
        }
    }
}

// ---------------- fused head, M=128: relu(concat@lin1+b) @ lin2 + b -> log_softmax ----------
// 512 threads (8 waves), 128 nodes/block, 96KB dynamic LDS. lin1 B prefetch 2-deep.
__global__ __launch_bounds__(512, 2) void k_final(
    const unsigned short* __restrict__ h1, const unsigned short* __restrict__ h2,
    const unsigned short* __restrict__ h3,
    const unsigned short* __restrict__ l1t, const float* __restrict__ l1b,
    const unsigned short* __restrict__ l2t, const float* __restrict__ l2b,
    float* __restrict__ out) {
    extern __shared__ __align__(16) char lds[];    // 128 * 768 = 96KB
    const int tid = threadIdx.x, lane = tid & 63, w = tid >> 6;
    const int l15 = lane & 15, lg = lane >> 4;
    const int nbase = blockIdx.x * 128;

    // stage concat(h1,h2,h3) tile: 12 x 1KB wave-loads direct to LDS per wave (96KB total)
    #pragma unroll
    for (int i = 0; i < 12; ++i) {
        unsigned byte = (unsigned)(w * 12288 + i * 1024 + lane * 16);
        unsigned r = byte / 768u;
        unsigned rem = byte - r * 768u;
        int c8 = (int)(rem >> 4) ^ (int)(r & 7);
        int part = c8 >> 4, c8p = c8 & 15;
        int slice = c8p >> 1, half = c8p & 1;
        int node = nbase + (int)r; if (node >= N_NODES) node = 0;
        const unsigned short* hp = part == 0 ? h1 : (part == 1 ? h2 : h3);
        gld16(hp + ((size_t)slice * N_NODES + node) * 16 + half * 8,
              lds + w * 12288 + i * 1024);
    }

    // preload lin1 B for ks=0,1 (2-deep; independent of staging)
    bf16x8 B[3][3];
    #pragma unroll
    for (int ot = 0; ot < 3; ++ot) {
        B[0][ot] = *(const bf16x8*)(l1t + ((size_t)((w * 3 + ot) * 12 + 0) * 64 + lane) * 8);
        B[1][ot] = *(const bf16x8*)(l1t + ((size_t)((w * 3 + ot) * 12 + 1) * 64 + lane) * 8);
    }
    __syncthreads();   // vmcnt(0) drains staging

    // lin1: wave w owns out cols [48w, 48w+48), 8 m-tiles; B rotated 2 ahead
    f32x4 acc[8][3];
    #pragma unroll
    for (int m = 0; m < 8; ++m)
        #pragma unroll
        for (int ot = 0; ot < 3; ++ot) acc[m][ot] = {0.f, 0.f, 0.f, 0.f};
    {
        #pragma unroll
        for (int ks = 0; ks < 12; ++ks) {
            int cur = ks % 3;
            if (ks < 10) {
                int nx2 = (ks + 2) % 3;
                #pragma unroll
                for (int ot = 0; ot < 3; ++ot)
                    B[nx2][ot] = *(const bf16x8*)(l1t + ((size_t)((w * 3 + ot) * 12 + ks + 2) * 64 + lane) * 8);
            }
            bf16x8 A[8];
            #pragma unroll
            for (int m = 0; m < 8; ++m) {
                int row = m * 16 + l15;
                A[m] = *(const bf16x8*)(lds + row * 768 + ((ks * 64 + lg * 16) ^ ((row & 7) << 4)));
            }
            #pragma unroll
            for (int ot = 0; ot < 3; ++ot)
                #pragma unroll
                for (int m = 0; m < 8; ++m)
                    acc[m][ot] = __builtin_amdgcn_mfma_f32_16x16x32_bf16(A[m], B[cur][ot], acc[m][ot], 0, 0, 0);
        }
    }
    __syncthreads();   // everyone done reading A-tile

    // relu + write hidden (bf16) into same LDS
    #pragma unroll
    for (int ot = 0; ot < 3; ++ot) {
        int c = (w * 3 + ot) * 16 + l15;
        float bias = l1b[c];
        #pragma unroll
        for (int m = 0; m < 8; ++m)
            #pragma unroll
            for (int r = 0; r < 4; ++r) {
                int row = m * 16 + lg * 4 + r;
                float v = acc[m][ot][r] + bias; v = v > 0.f ? v : 0.f;
                *(unsigned short*)(lds + row * 768 + ((c * 2) ^ ((row & 7) << 4))) = f2bf(v);
            }
    }
    __syncthreads();

    // lin2: wave w owns rows [16w, 16w+16); B+A double-buffered over ks
    f32x4 acc2[3];
    #pragma unroll
    for (int ot = 0; ot < 3; ++ot) acc2[ot] = {0.f, 0.f, 0.f, 0.f};
    {
        const int row = w * 16 + l15;
        bf16x8 C2[2][3]; bf16x8 A2[2];
        #pragma unroll
        for (int ot = 0; ot < 3; ++ot)
            C2[0][ot] = *(const bf16x8*)(l2t + ((size_t)(ot * 12) * 64 + lane) * 8);
        A2[0] = *(const bf16x8*)(lds + row * 768 + ((lg * 16) ^ ((row & 7) << 4)));
        #pragma unroll
        for (int ks = 0; ks < 12; ++ks) {
            int cur = ks & 1, nxt = cur ^ 1;
            if (ks < 11) {
                #pragma unroll
                for (int ot = 0; ot < 3; ++ot)
                    C2[nxt][ot] = *(const bf16x8*)(l2t + ((size_t)(ot * 12 + ks + 1) * 64 + lane) * 8);
                A2[nxt] = *(const bf16x8*)(lds + row * 768 + (((ks + 1) * 64 + lg * 16) ^ ((row & 7) << 4)));
            }
            #pragma unroll
            for (int ot = 0; ot < 3; ++ot)
                acc2[ot] = __builtin_amdgcn_mfma_f32_16x16x32_bf16(A2[cur], C2[cur][ot], acc2[ot], 0, 0, 0);
        }
    }

    // bias + log_softmax over 40 classes (row spread over 16 lanes x 3 regs)
    int c0 = l15;
    #pragma unroll
    for (int r = 0; r < 4; ++r) {
        float v0 = acc2[0][r] + l2b[c0];
        float v1 = acc2[1][r] + l2b[c0 + 16];
        float v2 = (c0 < 8) ? (acc2[2][r] + l2b[c0 + 32]) : -1e30f;
        float mx = fmaxf(fmaxf(v0, v1), v2);
        for (int msk = 1; msk < 16; msk <<= 1) mx = fmaxf(mx, __shfl_xor(mx, msk));
        float s = __expf(v0 - mx) + __expf(v1 - mx) + ((c0 < 8) ? __expf(v2 - mx) : 0.f);
        for (int msk = 1; msk < 16; msk <<= 1) s += __shfl_xor(s, msk);
        float lse = mx + __logf(s);
        int node = nbase + w * 16 + lg * 4 + r;
        if (node < N_NODES) {
            out[(size_t)node * 40 + c0] = v0 - lse;
            out[(size_t)node * 40 + c0 + 16] = v1 - lse;
            if (c0 < 8) out[(size_t)node * 40 + c0 + 32] = v2 - lse;
        }
    }
}

extern "C" void kernel_launch(void* const* d_in, const int* in_sizes, int n_in,
                              void* d_out, int out_size, void* d_ws, size_t ws_size,
                              hipStream_t stream) {
    const float* x  = (const float*)d_in[0];
    const int*   ei = (const int*)d_in[1];
    const float* gw1[3] = {(const float*)d_in[2],  (const float*)d_in[6],  (const float*)d_in[10]};
    const float* gb1[3] = {(const float*)d_in[3],  (const float*)d_in[7],  (const float*)d_in[11]};
    const float* gw2[3] = {(const float*)d_in[4],  (const float*)d_in[8],  (const float*)d_in[12]};
    const float* gb2[3] = {(const float*)d_in[5],  (const float*)d_in[9],  (const float*)d_in[13]};
    const float* l1w = (const float*)d_in[14];
    const float* l1b = (const float*)d_in[15];
    const float* l2w = (const float*)d_in[16];
    const float* l2b = (const float*)d_in[17];
    float* out = (float*)d_out;

    char* p = (char*)d_ws;
    auto alloc = [&](size_t bytes) { char* q = p; p += (bytes + 255) & ~(size_t)255; return q; };
    int* rp   = (int*)alloc(4 * (N_NODES + 1));
    int* cnt  = (int*)alloc(4 * N_NODES);
    int* bsum = (int*)alloc(4 * 256);
    int* colv = (int*)alloc(4 * (size_t)NEDGE);
    unsigned short* t  = (unsigned short*)alloc(2 * (size_t)N_NODES * 128);
    unsigned short* h1 = (unsigned short*)alloc(2 * (size_t)N_NODES * 128);
    unsigned short* h2 = (unsigned short*)alloc(2 * (size_t)N_NODES * 128);
    unsigned short* h3 = (unsigned short*)alloc(2 * (size_t)N_NODES * 128);
    unsigned short* xs = h3;   // alias: xs dead after layer-1 agg, h3 written in layer 3
    unsigned short* wt[6];
    for (int i = 0; i < 6; ++i) wt[i] = (unsigned short*)alloc(2 * 128 * 128);
    unsigned short* l1t = (unsigned short*)alloc(2 * 384 * 384);
    unsigned short* l2t = (unsigned short*)alloc(2 * 48 * 384);
    // note: wt[0..5], l1t, l2t are contiguous (each region a multiple of 256B) -> k_wprep_all

    // allow 96KB dynamic LDS for k_final (host-side attr set; not a stream op)
    static bool attr_set = false;
    if (!attr_set) {
        hipFuncSetAttribute((const void*)k_final,
                            hipFuncAttributeMaxDynamicSharedMemorySize, 128 * 768);
        attr_set = true;
    }

    const int nb = (N_NODES + 1023) / 1024;     // 98
    // CSR build
    k_zero<<<(N_NODES + 255) / 256, 256, 0, stream>>>(cnt, N_NODES);
    k_countr<<<((NEDGE + 255) / 256) * FILL_SLICES, 256, 0, stream>>>(ei, cnt);
    k_scan1<<<nb, 256, 0, stream>>>(cnt, rp, bsum);
    k_scan2<<<1, 256, 0, stream>>>(bsum, nb);
    k_scan3<<<nb, 256, 0, stream>>>(rp, bsum);
    k_zero<<<(N_NODES + 255) / 256, 256, 0, stream>>>(cnt, N_NODES);
    k_fillr<<<((NEDGE + 255) / 256) * FILL_SLICES, 256, 0, stream>>>(ei, rp, cnt, colv);

    // weight prep (one dispatch, fragment-major bf16)
    k_wprep_all<<<(WPREP_TOT + 255) / 256, 256, 0, stream>>>(
        gw1[0], gw2[0], gw1[1], gw2[1], gw1[2], gw2[2], l1w, l2w, wt[0]);

    // x -> sliced bf16
    k_xprep<<<8 * ((N_NODES * 8 + 255) / 256), 256, 0, stream>>>(x, xs);

    const int gagg = ((N_NODES + AGG_NODES - 1) / AGG_NODES) * 8;
    const int gtile = (N_NODES + 63) / 64;
    const int gtile2 = (N_NODES + 127) / 128;
    // layer 1
    k_aggs<<<gagg, 256, 0, stream>>>(xs, t, rp, colv);
    k_mlp<<<gtile, 256, 0, stream>>>(t, wt[0], gb1[0], wt[1], gb2[0], h1);
    // layer 2
    k_aggs<<<gagg, 256, 0, stream>>>(h1, t, rp, colv);
    k_mlp<<<gtile, 256, 0, stream>>>(t, wt[2], gb1[1], wt[3], gb2[1], h2);
    // layer 3
    k_aggs<<<gagg, 256, 0, stream>>>(h2, t, rp, colv);
    k_mlp<<<gtile, 256, 0, stream>>>(t, wt[4], gb1[2], wt[5], gb2[2], h3);
    // head
    k_final<<<gtile2, 512, 128 * 768, stream>>>(h1, h2, h3, l1t, l1b, l2t, l2b, out);
}